// Round 7
// baseline (206.814 us; speedup 1.0000x reference)
//
#include <hip/hip_runtime.h>
#include <math.h>

#define NPOS 4096   // H*W
#define MTOT 8192   // B*NPOS
#define KP   352    // padded feature dim (323 -> 352, mult of 32)
#define HT 64
#define WT 64
#define NSPLIT 2            // key-split factor for flash
#define KEYS_PER (NPOS / NSPLIT)   // 2048 keys per block
#define NCH (KEYS_PER / 64)        // 32 chunks

typedef unsigned short ushortT;
typedef short v8s __attribute__((ext_vector_type(8)));
typedef float v4f __attribute__((ext_vector_type(4)));
typedef unsigned uint2v __attribute__((ext_vector_type(2)));

static __device__ __forceinline__ ushortT bfr(float f) {
    union { float f; unsigned u; } v; v.f = f;
    return (ushortT)((v.u + 0x8000u) >> 16);
}
// round-half-up pack (projections)
static __device__ __forceinline__ unsigned pack2bf(float a, float b) {
    union { float f; unsigned u; } ua, ub; ua.f = a; ub.f = b;
    return __builtin_amdgcn_perm(ub.u + 0x8000u, ua.u + 0x8000u, 0x07060302u);
}
// truncating pack (P values; softmax-safe) — 1 instr
static __device__ __forceinline__ unsigned pack2bf_t(float a, float b) {
    union { float f; unsigned u; } ua, ub; ua.f = a; ub.f = b;
    return __builtin_amdgcn_perm(ub.u, ua.u, 0x07060302u);
}
static __device__ __forceinline__ float fexp2(float x) {
#if __has_builtin(__builtin_amdgcn_exp2f)
    return __builtin_amdgcn_exp2f(x);
#else
    return exp2f(x);
#endif
}
// unpack packed bf16 pair
static __device__ __forceinline__ float bflo(unsigned u) {
    union { unsigned u; float f; } v; v.u = u << 16; return v.f;
}
static __device__ __forceinline__ float bfhi(unsigned u) {
    union { unsigned u; float f; } v; v.u = u & 0xffff0000u; return v.f;
}

// ---------------- prep: d/gx/gy/PE -> F cols 256..351 (bf16), alpha fp32 ----------------
// minmax folded in; PE sin/cos via per-block LDS table (2048 distinct values, 8 trans/thread)
__global__ void k_prep(const float* __restrict__ dsm,
                       const float* __restrict__ walpha, const float* __restrict__ balpha,
                       ushortT* __restrict__ F, float* __restrict__ alpha) {
    __shared__ ushortT tab[64][32];   // [c][0..15]=sin(coord*w_i), [16..31]=cos(coord*w_i)
    __shared__ float smn[4], smx[4];

    int idx = blockIdx.x * 256 + threadIdx.x;    // global m, 0..8191
    int b = idx / NPOS, n = idx % NPOS;
    int hh = n / WT, ww = n % WT;
    const float* dp = dsm + (size_t)b * NPOS;
    const float l2w = 13.287712379549449f;  // log2(10000)

    // build PE table cooperatively: 2048 entries / 256 threads = 8 each
    {
        int t = threadIdx.x;
        #pragma unroll
        for (int e8 = 0; e8 < 8; e8++) {
            int e = t * 8 + e8;
            int c = e >> 5, j = e & 31, i = j & 15;
            float coord = -1.f + 2.f * (float)c / 63.f;
            float omega = exp2f(-(float)i * (l2w / 16.f));
            float v = (j < 16) ? __sinf(coord * omega) : __cosf(coord * omega);
            tab[c][j] = bfr(v);
        }
    }

    // in-block reduction of this batch's dsm min/max (16 KB, L2-hit after first block)
    float mn = 1e30f, mx = -1e30f;
    for (int i = threadIdx.x; i < NPOS; i += 256) {
        float v = dp[i];
        mn = fminf(mn, v); mx = fmaxf(mx, v);
    }
    for (int off = 32; off; off >>= 1) {
        mn = fminf(mn, __shfl_xor(mn, off, 64));
        mx = fmaxf(mx, __shfl_xor(mx, off, 64));
    }
    int wid = threadIdx.x >> 6;
    if ((threadIdx.x & 63) == 0) { smn[wid] = mn; smx[wid] = mx; }
    __syncthreads();   // tab + minmax partials complete
    float dmin = fminf(fminf(smn[0], smn[1]), fminf(smn[2], smn[3]));
    float dmax = fmaxf(fmaxf(smx[0], smx[1]), fmaxf(smx[2], smx[3]));
    float inv = 1.0f / (dmax - dmin + 1e-6f);

    float dwin[5][5];
    #pragma unroll
    for (int dy = 0; dy < 5; dy++)
        #pragma unroll
        for (int dx = 0; dx < 5; dx++) {
            int y = hh + dy - 2, x = ww + dx - 2;
            float v = 0.0f;
            if (y >= 0 && y < HT && x >= 0 && x < WT) v = (dp[y * WT + x] - dmin) * inv;
            dwin[dy][dx] = v;
        }

    float gxc = 0.f, gyc = 0.f;
    float conv = 0.f;
    #pragma unroll
    for (int oy = 0; oy < 3; oy++)
        #pragma unroll
        for (int ox = 0; ox < 3; ox++) {
            int qy = hh + oy - 1, qx = ww + ox - 1;
            float m = 0.0f;
            if (qy >= 0 && qy < HT && qx >= 0 && qx < WT) {
                float gx = dwin[oy][ox] - dwin[oy][ox + 2]
                         + 2.f * dwin[oy + 1][ox] - 2.f * dwin[oy + 1][ox + 2]
                         + dwin[oy + 2][ox] - dwin[oy + 2][ox + 2];
                float gy = dwin[oy][ox] + 2.f * dwin[oy][ox + 1] + dwin[oy][ox + 2]
                         - dwin[oy + 2][ox] - 2.f * dwin[oy + 2][ox + 1] - dwin[oy + 2][ox + 2];
                if (oy == 1 && ox == 1) { gxc = gx; gyc = gy; }
                float rx = fmaxf(gx, 0.f), ry = fmaxf(gy, 0.f);
                m = sqrtf(rx * rx + ry * ry + 1e-12f);
            }
            conv += walpha[oy * 3 + ox] * m;
        }
    alpha[idx] = 1.f / (1.f + __expf(-(conv + balpha[0])));

    ushortT* fb = F + (size_t)idx * KP;
    fb[256] = bfr(dwin[2][2]);
    fb[257] = bfr(gxc);
    fb[258] = bfr(gyc);
    // PE gather from LDS table (bit-identical to direct evaluation)
    #pragma unroll
    for (int i = 0; i < 32; i++) fb[259 + i] = tab[ww][i];   // sin(px), cos(px)
    #pragma unroll
    for (int i = 0; i < 32; i++) fb[291 + i] = tab[hh][i];   // sin(py), cos(py)
    #pragma unroll
    for (int z = 323; z < KP; z++) fb[z] = 0;
}

// ---------------- cast x -> F cols 0..255 (bf16, LDS transpose) ----------------
__global__ void k_cast(const float* __restrict__ x, ushortT* __restrict__ F) {
    __shared__ __align__(16) ushortT Tl[64][72];
    int nt = blockIdx.x * 64;
    int b = blockIdx.y >> 2, ct = (blockIdx.y & 3) * 64;
    int t = threadIdx.x;
    #pragma unroll
    for (int rep = 0; rep < 4; rep++) {
        int row = rep * 16 + (t >> 4), c4 = (t & 15) * 4;
        float4 f4 = *(const float4*)&x[((size_t)(b * 256 + ct + row)) * NPOS + nt + c4];
        Tl[c4 + 0][row] = bfr(f4.x);
        Tl[c4 + 1][row] = bfr(f4.y);
        Tl[c4 + 2][row] = bfr(f4.z);
        Tl[c4 + 3][row] = bfr(f4.w);
    }
    __syncthreads();
    #pragma unroll
    for (int rep = 0; rep < 2; rep++) {
        int slot = rep * 256 + t, row = slot >> 3, c8 = slot & 7;
        *(uint4*)&F[((size_t)(b * 4096 + nt + row)) * KP + ct + c8 * 8] = *(uint4*)&Tl[row][c8 * 8];
    }
}

// ---------------- combined weight Wc[1536][352] bf16 + bias fp32 (+ wout cast folded in) ----------------
__global__ void k_wcprep(const float* __restrict__ wq, const float* __restrict__ wkv,
                         const float* __restrict__ whape, const float* __restrict__ bhape,
                         const float* __restrict__ wout,
                         ushortT* __restrict__ Wc, float* __restrict__ biasc,
                         ushortT* __restrict__ woutb) {
    int idx = blockIdx.x * 256 + threadIdx.x;   // o*KP + k
    if (blockIdx.x < 512) {                     // 512*256 = 131072 = |wout|
        woutb[idx] = bfr(wout[idx]);
    }
    int o = idx / KP, k = idx % KP;
    float v = 0.f;
    if (o < 512) {
        if (k < 256) v = wq[o * 256 + k] * 0.18033688011112042f;  // 0.125 * log2(e)
        if (k == 0) biasc[o] = 0.f;
    } else if (o < 1024) {
        int r = o - 512;
        if (k < 257) v = wkv[r * 257 + k];
        if (k == 256)      v += whape[r * 67 + 64];
        else if (k == 257) v = whape[r * 67 + 65];
        else if (k == 258) v = whape[r * 67 + 66];
        else if (k >= 259 && k < 323) v = whape[r * 67 + (k - 259)];
        if (k == 0) biasc[o] = bhape[r];
    } else {
        int r = o - 512;
        if (k < 257) v = wkv[r * 257 + k];
        if (k == 0) biasc[o] = 0.f;
    }
    Wc[idx] = bfr(v);
}

// ---------------- GEMM1 (bf16 MFMA): [1536]x[352]x[8192] -> qT/kT/vv, 256x64 o-tiles ----------------
// o-tile 256 halves F re-reads (6 vs 12 passes) and doubles MFMA:ds_read ratio (16:8).
// Vt (transpose buffer for v) aliases Al/Bl staging — used only after the K-loop, barrier-protected.
__global__ __launch_bounds__(256) void k_gemm1(const ushortT* __restrict__ Wc, const ushortT* __restrict__ F,
                                               const float* __restrict__ biasc,
                                               ushortT* __restrict__ qT, ushortT* __restrict__ kT,
                                               ushortT* __restrict__ vv) {
    __shared__ __align__(16) char smem[256 * 72 * 2];            // 36864 B
    ushortT (*Al)[40] = (ushortT(*)[40])smem;                    // 256 rows x 32 cols (20480 B)
    ushortT (*Bl)[40] = (ushortT(*)[40])(smem + 20480);          // 64 rows x 32 cols (5120 B)
    ushortT (*Vt)[72] = (ushortT(*)[72])smem;                    // alias: 256 x 64 transpose

    int mt = blockIdx.x * 64;          // 128 m-tiles
    int ot = blockIdx.y * 256;         // 6 o-tiles (0-1: q, 2-3: k, 4-5: v)
    int t = threadIdx.x, w = t >> 6, lane = t & 63, u = lane & 15, quad = lane >> 4;
    v4f acc[4][4] = {};                // [rr][n4]
    for (int k0 = 0; k0 < KP; k0 += 32) {
        __syncthreads();
        #pragma unroll
        for (int rep = 0; rep < 4; rep++) {     // Al: 1024 uint4 slots
            int s = rep * 256 + t, row = s >> 2, ch = s & 3;
            *(uint4*)&Al[row][ch * 8] = *(const uint4*)&Wc[(size_t)(ot + row) * KP + k0 + ch * 8];
        }
        {                                        // Bl: 256 uint4 slots
            int row = t >> 2, ch = t & 3;
            *(uint4*)&Bl[row][ch * 8] = *(const uint4*)&F[(size_t)(mt + row) * KP + k0 + ch * 8];
        }
        __syncthreads();
        v8s a[4], bb[4];
        #pragma unroll
        for (int rr = 0; rr < 4; rr++) a[rr] = *(v8s*)&Al[w * 64 + rr * 16 + u][quad * 8];
        #pragma unroll
        for (int n4 = 0; n4 < 4; n4++) bb[n4] = *(v8s*)&Bl[n4 * 16 + u][quad * 8];
        #pragma unroll
        for (int rr = 0; rr < 4; rr++)
            #pragma unroll
            for (int n4 = 0; n4 < 4; n4++)
                acc[rr][n4] = __builtin_amdgcn_mfma_f32_16x16x32_bf16(a[rr], bb[n4], acc[rr][n4], 0, 0, 0);
    }
    float bo[4][4];
    #pragma unroll
    for (int rr = 0; rr < 4; rr++)
        #pragma unroll
        for (int r = 0; r < 4; r++) bo[rr][r] = biasc[ot + w * 64 + rr * 16 + quad * 4 + r];
    if (ot < 1024) {
        ushortT* dst = (ot < 512) ? qT : kT;
        #pragma unroll
        for (int rr = 0; rr < 4; rr++) {
            int oo = ot + w * 64 + rr * 16;
            int h = (oo >> 6) & 7;
            int dcol = (oo & 63) + quad * 4;
            #pragma unroll
            for (int n4 = 0; n4 < 4; n4++) {
                int m = mt + n4 * 16 + u;
                uint2 val;
                val.x = pack2bf(acc[rr][n4][0] + bo[rr][0], acc[rr][n4][1] + bo[rr][1]);
                val.y = pack2bf(acc[rr][n4][2] + bo[rr][2], acc[rr][n4][3] + bo[rr][3]);
                *(uint2*)&dst[((size_t)h * MTOT + m) * 64 + dcol] = val;
            }
        }
    } else {
        __syncthreads();   // all waves done reading Al/Bl before Vt overwrites
        #pragma unroll
        for (int rr = 0; rr < 4; rr++)
            #pragma unroll
            for (int n4 = 0; n4 < 4; n4++) {
                int ml = n4 * 16 + u;
                #pragma unroll
                for (int r = 0; r < 4; r++)
                    Vt[w * 64 + rr * 16 + quad * 4 + r][ml] = bfr(acc[rr][n4][r] + bo[rr][r]);
            }
        __syncthreads();
        #pragma unroll
        for (int rep = 0; rep < 8; rep++) {     // 2048 uint4 slots
            int slot = rep * 256 + t, row = slot >> 3, c8 = slot & 7;
            *(uint4*)&vv[(size_t)(ot - 1024 + row) * MTOT + mt + c8 * 8] = *(uint4*)&Vt[row][c8 * 8];
        }
    }
}

// ---------------- flash attention: 32q/wave, register-staged K/V (double-buffered),
// T14 order; P in registers; li via ones-MFMA; hoisted LDS offsets; T5 setprio; bf16 Opart ----------------
#define LIDX(row, cb) (((row) << 6) + ((((cb) ^ ((row) & 7))) << 3))
__global__ __launch_bounds__(256, 4) void k_flash(const ushortT* __restrict__ qT,
                                                  const ushortT* __restrict__ kT,
                                                  const ushortT* __restrict__ vv,
                                                  ushortT* __restrict__ Opart,
                                                  float* __restrict__ liPart) {
    __shared__ __align__(16) ushortT Kbuf[2][64 * 64];   // 8 KB each
    __shared__ __align__(16) ushortT Vbuf[2][64 * 64];   // total LDS = 32 KB

    int it = blockIdx.x;            // 0..31 (128-query tiles)
    int bh = blockIdx.y;
    int half = blockIdx.z;          // key half: 0..NSPLIT-1
    int b = bh >> 3, h = bh & 7;
    int colbase = b * NPOS;
    int t = threadIdx.x, w = t >> 6, lane = t & 63, u = lane & 15, quad = lane >> 4;
    int qb = it * 128 + w * 32;     // wave's query base within batch

    const ushortT* Qg = qT + ((size_t)h * MTOT + colbase + qb) * 64;
    const ushortT* Kg = kT + ((size_t)h * MTOT + colbase + half * KEYS_PER) * 64;
    const ushortT* Vg = vv + ((size_t)(h * 64)) * MTOT + colbase + half * KEYS_PER;

    // staging slots (2 per thread for K, 2 for V)
    int row0 = t >> 3, c80 = t & 7;       // slot t
    int row1 = 32 + row0;                 // slot 256+t (same c8)

    // hoisted LDS byte offsets (loop-invariant; K and V reads share them)
    unsigned boff[4][2];
    #pragma unroll
    for (int i4 = 0; i4 < 4; i4++) {
        boff[i4][0] = 2u * (unsigned)LIDX(i4 * 16 + u, quad);
        boff[i4][1] = 2u * (unsigned)LIDX(i4 * 16 + u, 4 + quad);
        asm volatile("" : "+v"(boff[i4][0]), "+v"(boff[i4][1]));
    }
    unsigned woff0 = 2u * (unsigned)LIDX(row0, c80);
    unsigned woff1 = 2u * (unsigned)LIDX(row1, c80);
    asm volatile("" : "+v"(woff0), "+v"(woff1));

    // Q fragments resident in registers (32 queries -> 2 g-groups)
    v8s bq[2][2];
    #pragma unroll
    for (int g = 0; g < 2; g++)
        #pragma unroll
        for (int hf = 0; hf < 2; hf++)
            bq[g][hf] = *(const v8s*)&Qg[(size_t)(g * 16 + u) * 64 + hf * 32 + quad * 8];

    // all-ones bf16 A-fragment: mfma(ones, P, li4) -> every row of li4 = sum_k P[k][q]
    v8s ones;
    #pragma unroll
    for (int i = 0; i < 8; i++) ones[i] = (short)0x3F80;

    v4f li4[2] = {};    // [g]: rows redundant, col = query u
    v4f O[4][2] = {};   // [d4][g]

    // prologue: prefetch chunk 0 into registers
    uint4 kr0 = *(const uint4*)&Kg[(size_t)row0 * 64 + c80 * 8];
    uint4 kr1 = *(const uint4*)&Kg[(size_t)row1 * 64 + c80 * 8];
    uint4 vr0 = *(const uint4*)&Vg[(size_t)row0 * MTOT + c80 * 8];
    uint4 vr1 = *(const uint4*)&Vg[(size_t)row1 * MTOT + c80 * 8];

    #pragma unroll 2
    for (int jc = 0; jc < NCH; jc++) {
        int cur = jc & 1;
        char* KbW = (char*)&Kbuf[cur][0];
        char* VbW = (char*)&Vbuf[cur][0];
        // write staged regs to LDS buffer `cur` (regs are a full compute-phase old: no vm stall)
        *(uint4*)(KbW + woff0) = kr0;
        *(uint4*)(KbW + woff1) = kr1;
        *(uint4*)(VbW + woff0) = vr0;
        *(uint4*)(VbW + woff1) = vr1;
        __syncthreads();   // buf `cur` visible to all; vmcnt already 0 -> no drain stall
        // issue next-chunk prefetch NOW: latency hides under the compute below
        if (jc + 1 < NCH) {
            int jb = (jc + 1) * 64;
            kr0 = *(const uint4*)&Kg[(size_t)(jb + row0) * 64 + c80 * 8];
            kr1 = *(const uint4*)&Kg[(size_t)(jb + row1) * 64 + c80 * 8];
            vr0 = *(const uint4*)&Vg[(size_t)row0 * MTOT + jb + c80 * 8];
            vr1 = *(const uint4*)&Vg[(size_t)row1 * MTOT + jb + c80 * 8];
        }

        const char* Kb = (const char*)&Kbuf[cur][0];
        const char* Vb = (const char*)&Vbuf[cur][0];

        // S^T strips + softmax; P packed in registers, redistributed per k4-PAIR
        v8s bp[2][2];
        #pragma unroll
        for (int kp = 0; kp < 2; kp++) {
            unsigned pk0[2][2], pk1[2][2];   // [g][kk]
            #pragma unroll
            for (int kk = 0; kk < 2; kk++) {
                int k4 = kp * 2 + kk;
                v8s ak0 = *(const v8s*)(Kb + boff[k4][0]);
                v8s ak1 = *(const v8s*)(Kb + boff[k4][1]);
                v4f st[2];
                __builtin_amdgcn_s_setprio(1);
                #pragma unroll
                for (int g = 0; g < 2; g++) {
                    st[g] = (v4f){0.f, 0.f, 0.f, 0.f};
                    st[g] = __builtin_amdgcn_mfma_f32_16x16x32_bf16(ak0, bq[g][0], st[g], 0, 0, 0);
                    st[g] = __builtin_amdgcn_mfma_f32_16x16x32_bf16(ak1, bq[g][1], st[g], 0, 0, 0);
                }
                __builtin_amdgcn_s_setprio(0);
                #pragma unroll
                for (int g = 0; g < 2; g++) {
                    float p0 = fexp2(st[g][0]);
                    float p1 = fexp2(st[g][1]);
                    float p2 = fexp2(st[g][2]);
                    float p3 = fexp2(st[g][3]);
                    pk0[g][kk] = pack2bf_t(p0, p1);
                    pk1[g][kk] = pack2bf_t(p2, p3);
                }
            }
            // in-register redistribution (bit-exact verified)
            #pragma unroll
            for (int g = 0; g < 2; g++) {
                uint2v r0s = __builtin_amdgcn_permlane32_swap(pk0[g][0], pk0[g][1], false, false);
                uint2v r1s = __builtin_amdgcn_permlane32_swap(pk1[g][0], pk1[g][1], false, false);
                uint2v t0 = __builtin_amdgcn_permlane16_swap(r0s.x, r0s.y, false, false);
                uint2v t1 = __builtin_amdgcn_permlane16_swap(r1s.x, r1s.y, false, false);
                union { uint4 u4; v8s s; } cv;
                cv.u4.x = t0.x; cv.u4.y = t1.x; cv.u4.z = t0.y; cv.u4.w = t1.y;
                bp[g][kp] = cv.s;
            }
        }

        // li + PV on the MFMA pipe (T5: boost while in pure-MFMA cluster)
        __builtin_amdgcn_s_setprio(1);
        #pragma unroll
        for (int g = 0; g < 2; g++) {
            li4[g] = __builtin_amdgcn_mfma_f32_16x16x32_bf16(ones, bp[g][0], li4[g], 0, 0, 0);
            li4[g] = __builtin_amdgcn_mfma_f32_16x16x32_bf16(ones, bp[g][1], li4[g], 0, 0, 0);
        }
        #pragma unroll
        for (int d4 = 0; d4 < 4; d4++) {
            v8s av0 = *(const v8s*)(Vb + boff[d4][0]);
            v8s av1 = *(const v8s*)(Vb + boff[d4][1]);
            #pragma unroll
            for (int g = 0; g < 2; g++) {
                O[d4][g] = __builtin_amdgcn_mfma_f32_16x16x32_bf16(av0, bp[g][0], O[d4][g], 0, 0, 0);
                O[d4][g] = __builtin_amdgcn_mfma_f32_16x16x32_bf16(av1, bp[g][1], O[d4][g], 0, 0, 0);
            }
        }
        __builtin_amdgcn_s_setprio(0);
    }

    // epilogue: store UNNORMALIZED O (bf16, halves traffic) + li partials (lane holds li[q=u])
    #pragma unroll
    for (int g = 0; g < 2; g++) {
        int q = qb + g * 16 + u;
        size_t m2 = (size_t)(half * 2 + b) * 4096 + q;   // = half*8192 + m
        size_t base = m2 * 512 + h * 64;
        #pragma unroll
        for (int d4 = 0; d4 < 4; d4++) {
            uint2 o2;
            o2.x = pack2bf(O[d4][g][0], O[d4][g][1]);
            o2.y = pack2bf(O[d4][g][2], O[d4][g][3]);
            *(uint2*)&Opart[base + d4 * 16 + quad * 4] = o2;
        }
        if (quad == 0) liPart[m2 * 8 + h] = li4[g][0];
    }
}

// ---------------- combine the key-halves (bf16 partials) -> aoB bf16 [m][512] ----------------
__global__ __launch_bounds__(256) void k_comb(const ushortT* __restrict__ Opart,
                                              const float* __restrict__ liPart,
                                              ushortT* __restrict__ aoB) {
    int tid = blockIdx.x * 256 + threadIdx.x;   // 8192*128
    int m = tid >> 7, c4 = (tid & 127) * 4, h = c4 >> 6;
    float l = 0.f;
    #pragma unroll
    for (int s = 0; s < NSPLIT; s++) l += liPart[((size_t)s * 8192 + m) * 8 + h];
    float inv = 1.f / l;
    float ox = 0.f, oy = 0.f, oz = 0.f, ow = 0.f;
    #pragma unroll
    for (int s = 0; s < NSPLIT; s++) {
        uint2 o = *(const uint2*)&Opart[((size_t)s * 8192 + m) * 512 + c4];
        ox += bflo(o.x); oy += bfhi(o.x);
        oz += bflo(o.y); ow += bfhi(o.y);
    }
    uint2 val;
    val.x = pack2bf(ox * inv, oy * inv);
    val.y = pack2bf(oz * inv, ow * inv);
    *(uint2*)&aoB[(size_t)m * 512 + c4] = val;
}

// ---------------- GEMM2 (bf16 MFMA): out = x + (wout*AO + bout)*alpha ----------------
__global__ __launch_bounds__(256) void k_gemm2(const ushortT* __restrict__ woutb, const ushortT* __restrict__ aoB,
                                               const float* __restrict__ bout, const float* __restrict__ x,
                                               const float* __restrict__ alpha, float* __restrict__ out) {
    __shared__ __align__(16) ushortT Al[64][40];
    __shared__ __align__(16) ushortT Bl[64][40];
    int mt = blockIdx.x * 64;
    int ot = blockIdx.y * 64;
    int t = threadIdx.x, w = t >> 6, lane = t & 63, u = lane & 15, quad = lane >> 4;
    int arow = t >> 2, ac8 = t & 3;
    v4f acc[4] = {};
    for (int k0 = 0; k0 < 512; k0 += 32) {
        __syncthreads();
        *(uint4*)&Al[arow][ac8 * 8] = *(const uint4*)&woutb[(size_t)(ot + arow) * 512 + k0 + ac8 * 8];
        *(uint4*)&Bl[arow][ac8 * 8] = *(const uint4*)&aoB[(size_t)(mt + arow) * 512 + k0 + ac8 * 8];
        __syncthreads();
        v8s a = *(v8s*)&Al[w * 16 + u][quad * 8];
        #pragma unroll
        for (int n4 = 0; n4 < 4; n4++) {
            v8s bb = *(v8s*)&Bl[n4 * 16 + u][quad * 8];
            acc[n4] = __builtin_amdgcn_mfma_f32_16x16x32_bf16(a, bb, acc[n4], 0, 0, 0);
        }
    }
    int b = mt >> 12, n0 = mt & 4095;
    int obase = ot + w * 16 + quad * 4;
    float bo[4];
    #pragma unroll
    for (int r = 0; r < 4; r++) bo[r] = bout[obase + r];
    #pragma unroll
    for (int n4 = 0; n4 < 4; n4++) {
        int n = n0 + n4 * 16 + u;
        float al = alpha[(size_t)b * NPOS + n];
        #pragma unroll
        for (int r = 0; r < 4; r++) {
            size_t xi = ((size_t)(b * 256 + obase + r)) * NPOS + n;
            out[xi] = x[xi] + (acc[n4][r] + bo[r]) * al;
        }
    }
}

extern "C" void kernel_launch(void* const* d_in, const int* in_sizes, int n_in,
                              void* d_out, int out_size, void* d_ws, size_t ws_size,
                              hipStream_t stream) {
    const float* x      = (const float*)d_in[0];
    const float* dsm    = (const float*)d_in[1];
    const float* wq     = (const float*)d_in[2];
    const float* wkv    = (const float*)d_in[3];
    const float* wout   = (const float*)d_in[4];
    const float* bout   = (const float*)d_in[5];
    const float* whape  = (const float*)d_in[6];
    const float* bhape  = (const float*)d_in[7];
    const float* walpha = (const float*)d_in[8];
    const float* balpha = (const float*)d_in[9];
    float* out = (float*)d_out;
    float* ws  = (float*)d_ws;

    size_t off = 0;
    float* alpha = ws + off; off += (size_t)2 * NPOS;
    float* biasc = ws + off; off += 2048;
    float* liPart = ws + off; off += (size_t)NSPLIT * MTOT * 8;     // fp32 partial li
    ushortT* Opart = (ushortT*)(ws + off); off += (size_t)NSPLIT * MTOT * 512 / 2;  // bf16 partial O (16.7 MB)
    ushortT* F     = (ushortT*)(ws + off); off += (size_t)MTOT * KP / 2;
    ushortT* Wc    = (ushortT*)(ws + off); off += (size_t)1536 * KP / 2;
    ushortT* woutb = (ushortT*)(ws + off); off += (size_t)256 * 512 / 2;
    ushortT* qT    = (ushortT*)(ws + off); off += (size_t)8 * MTOT * 64 / 2;
    ushortT* kT    = (ushortT*)(ws + off); off += (size_t)8 * MTOT * 64 / 2;
    ushortT* vv    = (ushortT*)(ws + off); off += (size_t)512 * MTOT / 2;
    ushortT* aoB   = (ushortT*)(ws + off); off += (size_t)MTOT * 512 / 2;
    (void)in_sizes; (void)n_in; (void)out_size; (void)ws_size;

    k_prep<<<32, 256, 0, stream>>>(dsm, walpha, balpha, F, alpha);
    k_cast<<<dim3(64, 8), 256, 0, stream>>>(x, F);
    k_wcprep<<<(1536 * KP) / 256, 256, 0, stream>>>(wq, wkv, whape, bhape, wout, Wc, biasc, woutb);
    k_gemm1<<<dim3(128, 6), 256, 0, stream>>>(Wc, F, biasc, qT, kT, vv);
    k_flash<<<dim3(32, 16, NSPLIT), 256, 0, stream>>>(qT, kT, vv, Opart, liPart);
    k_comb<<<4096, 256, 0, stream>>>(Opart, liPart, aoB);
    k_gemm2<<<dim3(128, 4), 256, 0, stream>>>(woutb, aoB, bout, x, alpha, out);
}

// Round 8
// 201.511 us; speedup vs baseline: 1.0263x; 1.0263x over previous
//
#include <hip/hip_runtime.h>
#include <math.h>

#define NPOS 4096   // H*W
#define MTOT 8192   // B*NPOS
#define KP   352    // padded feature dim (323 -> 352, mult of 32)
#define HT 64
#define WT 64
#define NSPLIT 2            // key-split factor for flash
#define KEYS_PER (NPOS / NSPLIT)   // 2048 keys per block
#define NCH (KEYS_PER / 64)        // 32 chunks

// F layout: cols 0..255 = x (bf16), 256..319 = PE [sin px, cos px, sin py, cos py],
//           320 = d, 321 = gx, 322 = gy, 323..351 = 0.  (Wc permuted to match.)

typedef unsigned short ushortT;
typedef short v8s __attribute__((ext_vector_type(8)));
typedef float v4f __attribute__((ext_vector_type(4)));
typedef unsigned uint2v __attribute__((ext_vector_type(2)));

static __device__ __forceinline__ ushortT bfr(float f) {
    union { float f; unsigned u; } v; v.f = f;
    return (ushortT)((v.u + 0x8000u) >> 16);
}
// round-half-up pack; low short = a
static __device__ __forceinline__ unsigned pack2bf(float a, float b) {
    union { float f; unsigned u; } ua, ub; ua.f = a; ub.f = b;
    return __builtin_amdgcn_perm(ub.u + 0x8000u, ua.u + 0x8000u, 0x07060302u);
}
// truncating pack (P values; softmax-safe)
static __device__ __forceinline__ unsigned pack2bf_t(float a, float b) {
    union { float f; unsigned u; } ua, ub; ua.f = a; ub.f = b;
    return __builtin_amdgcn_perm(ub.u, ua.u, 0x07060302u);
}
static __device__ __forceinline__ float fexp2(float x) {
#if __has_builtin(__builtin_amdgcn_exp2f)
    return __builtin_amdgcn_exp2f(x);
#else
    return exp2f(x);
#endif
}
static __device__ __forceinline__ float bflo(unsigned u) {
    union { unsigned u; float f; } v; v.u = u << 16; return v.f;
}
static __device__ __forceinline__ float bfhi(unsigned u) {
    union { unsigned u; float f; } v; v.u = u & 0xffff0000u; return v.f;
}

// ---------------- fused preprocessing: prep (32) | cast (512) | wcprep (2112) ----------------
// Roles are independent (disjoint outputs); fusing hides prep's latency under cast's streaming
// and removes two launch gaps.
__global__ void k_pre(const float* __restrict__ dsm,
                      const float* __restrict__ walpha, const float* __restrict__ balpha,
                      const float* __restrict__ x,
                      const float* __restrict__ wq, const float* __restrict__ wkv,
                      const float* __restrict__ whape, const float* __restrict__ bhape,
                      const float* __restrict__ wout,
                      ushortT* __restrict__ F, float* __restrict__ alpha,
                      ushortT* __restrict__ Wc, float* __restrict__ biasc,
                      ushortT* __restrict__ woutb) {
    __shared__ __align__(16) ushortT Tl[64][72];
    __shared__ float smn[4], smx[4];
    int role = blockIdx.x;
    int t = threadIdx.x;

    if (role < 32) {
        // ---- prep: d/gx/gy/PE -> F cols 256..351, alpha ----
        int idx = role * 256 + t;               // global m
        int b = idx / NPOS, n = idx % NPOS;
        int hh = n / WT, ww = n % WT;
        const float* dp = dsm + (size_t)b * NPOS;

        float mn = 1e30f, mx = -1e30f;
        for (int i = t; i < NPOS; i += 256) {
            float v = dp[i];
            mn = fminf(mn, v); mx = fmaxf(mx, v);
        }
        for (int off = 32; off; off >>= 1) {
            mn = fminf(mn, __shfl_xor(mn, off, 64));
            mx = fmaxf(mx, __shfl_xor(mx, off, 64));
        }
        int wid = t >> 6;
        if ((t & 63) == 0) { smn[wid] = mn; smx[wid] = mx; }
        __syncthreads();
        float dmin = fminf(fminf(smn[0], smn[1]), fminf(smn[2], smn[3]));
        float dmax = fmaxf(fmaxf(smx[0], smx[1]), fmaxf(smx[2], smx[3]));
        float inv = 1.0f / (dmax - dmin + 1e-6f);

        float dwin[5][5];
        #pragma unroll
        for (int dy = 0; dy < 5; dy++)
            #pragma unroll
            for (int dx = 0; dx < 5; dx++) {
                int y = hh + dy - 2, xx = ww + dx - 2;
                float v = 0.0f;
                if (y >= 0 && y < HT && xx >= 0 && xx < WT) v = (dp[y * WT + xx] - dmin) * inv;
                dwin[dy][dx] = v;
            }

        float gxc = 0.f, gyc = 0.f, conv = 0.f;
        #pragma unroll
        for (int oy = 0; oy < 3; oy++)
            #pragma unroll
            for (int ox = 0; ox < 3; ox++) {
                int qy = hh + oy - 1, qx = ww + ox - 1;
                float m = 0.0f;
                if (qy >= 0 && qy < HT && qx >= 0 && qx < WT) {
                    float gx = dwin[oy][ox] - dwin[oy][ox + 2]
                             + 2.f * dwin[oy + 1][ox] - 2.f * dwin[oy + 1][ox + 2]
                             + dwin[oy + 2][ox] - dwin[oy + 2][ox + 2];
                    float gy = dwin[oy][ox] + 2.f * dwin[oy][ox + 1] + dwin[oy][ox + 2]
                             - dwin[oy + 2][ox] - 2.f * dwin[oy + 2][ox + 1] - dwin[oy + 2][ox + 2];
                    if (oy == 1 && ox == 1) { gxc = gx; gyc = gy; }
                    float rx = fmaxf(gx, 0.f), ry = fmaxf(gy, 0.f);
                    m = sqrtf(rx * rx + ry * ry + 1e-12f);
                }
                conv += walpha[oy * 3 + ox] * m;
            }
        alpha[idx] = 1.f / (1.f + __expf(-(conv + balpha[0])));

        // PE assembled in registers -> 8 x uint4 coalesced stores (col 256 = byte 512, 16B-aligned)
        float xc = -1.f + 2.f * (float)ww / 63.f;
        float yc = -1.f + 2.f * (float)hh / 63.f;
        const float l2w = 13.287712379549449f;  // log2(10000)
        unsigned pe[32];
        #pragma unroll
        for (int i = 0; i < 16; i += 2) {
            float w0 = exp2f(-(float)i * (l2w / 16.f));
            float w1 = exp2f(-(float)(i + 1) * (l2w / 16.f));
            pe[i / 2]      = pack2bf(__sinf(xc * w0), __sinf(xc * w1));
            pe[8 + i / 2]  = pack2bf(__cosf(xc * w0), __cosf(xc * w1));
            pe[16 + i / 2] = pack2bf(__sinf(yc * w0), __sinf(yc * w1));
            pe[24 + i / 2] = pack2bf(__cosf(yc * w0), __cosf(yc * w1));
        }
        ushortT* fb = F + (size_t)idx * KP;
        uint4* dst = (uint4*)(fb + 256);
        #pragma unroll
        for (int q = 0; q < 8; q++) dst[q] = *(uint4*)&pe[q * 4];
        *(unsigned*)(fb + 320) = pack2bf(dwin[2][2], gxc);   // d, gx
        fb[322] = bfr(gyc);
        fb[323] = 0;
        *(unsigned*)(fb + 324) = 0;
        *(unsigned*)(fb + 326) = 0;
        uint4 z4 = {0, 0, 0, 0};
        *(uint4*)(fb + 328) = z4;
        *(uint4*)(fb + 336) = z4;
        *(uint4*)(fb + 344) = z4;
    } else if (role < 544) {
        // ---- cast: x -> F cols 0..255 (LDS transpose) ----
        int bid = role - 32;
        int nt = (bid & 63) * 64;
        int by = bid >> 6;
        int b = by >> 2, ct = (by & 3) * 64;
        #pragma unroll
        for (int rep = 0; rep < 4; rep++) {
            int row = rep * 16 + (t >> 4), c4 = (t & 15) * 4;
            float4 f4 = *(const float4*)&x[((size_t)(b * 256 + ct + row)) * NPOS + nt + c4];
            Tl[c4 + 0][row] = bfr(f4.x);
            Tl[c4 + 1][row] = bfr(f4.y);
            Tl[c4 + 2][row] = bfr(f4.z);
            Tl[c4 + 3][row] = bfr(f4.w);
        }
        __syncthreads();
        #pragma unroll
        for (int rep = 0; rep < 2; rep++) {
            int slot = rep * 256 + t, row = slot >> 3, c8 = slot & 7;
            *(uint4*)&F[((size_t)(b * 4096 + nt + row)) * KP + ct + c8 * 8] = *(uint4*)&Tl[row][c8 * 8];
        }
    } else {
        // ---- wcprep: combined weight Wc + biasc (+ wout cast) ----
        int bid = role - 544;
        int idx = bid * 256 + t;                // o*KP + k
        if (bid < 512) woutb[idx] = bfr(wout[idx]);
        int o = idx / KP, k = idx % KP;
        float v = 0.f;
        if (o < 512) {
            if (k < 256) v = wq[o * 256 + k] * 0.18033688011112042f;  // 0.125 * log2(e)
            if (k == 0) biasc[o] = 0.f;
        } else if (o < 1024) {
            int r = o - 512;
            if (k < 256) v = wkv[r * 257 + k];
            else if (k < 320) v = whape[r * 67 + (k - 256)];
            else if (k == 320) v = wkv[r * 257 + 256] + whape[r * 67 + 64];
            else if (k == 321) v = whape[r * 67 + 65];
            else if (k == 322) v = whape[r * 67 + 66];
            if (k == 0) biasc[o] = bhape[r];
        } else {
            int r = o - 512;
            if (k < 256) v = wkv[r * 257 + k];
            else if (k == 320) v = wkv[r * 257 + 256];
            if (k == 0) biasc[o] = 0.f;
        }
        Wc[idx] = bfr(v);
    }
}

// ---------------- GEMM1 (bf16 MFMA): [1536]x[352]x[8192] -> qT/kT/vv, 256x64 o-tiles ----------------
__global__ __launch_bounds__(256) void k_gemm1(const ushortT* __restrict__ Wc, const ushortT* __restrict__ F,
                                               const float* __restrict__ biasc,
                                               ushortT* __restrict__ qT, ushortT* __restrict__ kT,
                                               ushortT* __restrict__ vv) {
    __shared__ __align__(16) char smem[256 * 72 * 2];            // 36864 B
    ushortT (*Al)[40] = (ushortT(*)[40])smem;                    // 256 x 32 staged
    ushortT (*Bl)[40] = (ushortT(*)[40])(smem + 20480);          // 64 x 32 staged
    ushortT (*Vt)[72] = (ushortT(*)[72])smem;                    // alias: 256 x 64 transpose

    int mt = blockIdx.x * 64;
    int ot = blockIdx.y * 256;         // 0-1: q, 2-3: k, 4-5: v
    int t = threadIdx.x, w = t >> 6, lane = t & 63, u = lane & 15, quad = lane >> 4;
    v4f acc[4][4] = {};
    for (int k0 = 0; k0 < KP; k0 += 32) {
        __syncthreads();
        #pragma unroll
        for (int rep = 0; rep < 4; rep++) {
            int s = rep * 256 + t, row = s >> 2, ch = s & 3;
            *(uint4*)&Al[row][ch * 8] = *(const uint4*)&Wc[(size_t)(ot + row) * KP + k0 + ch * 8];
        }
        {
            int row = t >> 2, ch = t & 3;
            *(uint4*)&Bl[row][ch * 8] = *(const uint4*)&F[(size_t)(mt + row) * KP + k0 + ch * 8];
        }
        __syncthreads();
        v8s a[4], bb[4];
        #pragma unroll
        for (int rr = 0; rr < 4; rr++) a[rr] = *(v8s*)&Al[w * 64 + rr * 16 + u][quad * 8];
        #pragma unroll
        for (int n4 = 0; n4 < 4; n4++) bb[n4] = *(v8s*)&Bl[n4 * 16 + u][quad * 8];
        #pragma unroll
        for (int rr = 0; rr < 4; rr++)
            #pragma unroll
            for (int n4 = 0; n4 < 4; n4++)
                acc[rr][n4] = __builtin_amdgcn_mfma_f32_16x16x32_bf16(a[rr], bb[n4], acc[rr][n4], 0, 0, 0);
    }
    float bo[4][4];
    #pragma unroll
    for (int rr = 0; rr < 4; rr++)
        #pragma unroll
        for (int r = 0; r < 4; r++) bo[rr][r] = biasc[ot + w * 64 + rr * 16 + quad * 4 + r];
    if (ot < 1024) {
        ushortT* dst = (ot < 512) ? qT : kT;
        #pragma unroll
        for (int rr = 0; rr < 4; rr++) {
            int oo = ot + w * 64 + rr * 16;
            int h = (oo >> 6) & 7;
            int dcol = (oo & 63) + quad * 4;
            #pragma unroll
            for (int n4 = 0; n4 < 4; n4++) {
                int m = mt + n4 * 16 + u;
                uint2 val;
                val.x = pack2bf(acc[rr][n4][0] + bo[rr][0], acc[rr][n4][1] + bo[rr][1]);
                val.y = pack2bf(acc[rr][n4][2] + bo[rr][2], acc[rr][n4][3] + bo[rr][3]);
                *(uint2*)&dst[((size_t)h * MTOT + m) * 64 + dcol] = val;
            }
        }
    } else {
        __syncthreads();
        #pragma unroll
        for (int rr = 0; rr < 4; rr++)
            #pragma unroll
            for (int n4 = 0; n4 < 4; n4++) {
                int ml = n4 * 16 + u;
                #pragma unroll
                for (int r = 0; r < 4; r++)
                    Vt[w * 64 + rr * 16 + quad * 4 + r][ml] = bfr(acc[rr][n4][r] + bo[rr][r]);
            }
        __syncthreads();
        #pragma unroll
        for (int rep = 0; rep < 8; rep++) {
            int slot = rep * 256 + t, row = slot >> 3, c8 = slot & 7;
            *(uint4*)&vv[(size_t)(ot - 1024 + row) * MTOT + mt + c8 * 8] = *(uint4*)&Vt[row][c8 * 8];
        }
    }
}

// ---------------- flash attention (as round 7: reg-staged dbuf, reg-P, ones-MFMA li,
// hoisted offsets, setprio, bf16 Opart) ----------------
#define LIDX(row, cb) (((row) << 6) + ((((cb) ^ ((row) & 7))) << 3))
__global__ __launch_bounds__(256, 4) void k_flash(const ushortT* __restrict__ qT,
                                                  const ushortT* __restrict__ kT,
                                                  const ushortT* __restrict__ vv,
                                                  ushortT* __restrict__ Opart,
                                                  float* __restrict__ liPart) {
    __shared__ __align__(16) ushortT Kbuf[2][64 * 64];
    __shared__ __align__(16) ushortT Vbuf[2][64 * 64];

    int it = blockIdx.x;
    int bh = blockIdx.y;
    int half = blockIdx.z;
    int b = bh >> 3, h = bh & 7;
    int colbase = b * NPOS;
    int t = threadIdx.x, w = t >> 6, lane = t & 63, u = lane & 15, quad = lane >> 4;
    int qb = it * 128 + w * 32;

    const ushortT* Qg = qT + ((size_t)h * MTOT + colbase + qb) * 64;
    const ushortT* Kg = kT + ((size_t)h * MTOT + colbase + half * KEYS_PER) * 64;
    const ushortT* Vg = vv + ((size_t)(h * 64)) * MTOT + colbase + half * KEYS_PER;

    int row0 = t >> 3, c80 = t & 7;
    int row1 = 32 + row0;

    unsigned boff[4][2];
    #pragma unroll
    for (int i4 = 0; i4 < 4; i4++) {
        boff[i4][0] = 2u * (unsigned)LIDX(i4 * 16 + u, quad);
        boff[i4][1] = 2u * (unsigned)LIDX(i4 * 16 + u, 4 + quad);
        asm volatile("" : "+v"(boff[i4][0]), "+v"(boff[i4][1]));
    }
    unsigned woff0 = 2u * (unsigned)LIDX(row0, c80);
    unsigned woff1 = 2u * (unsigned)LIDX(row1, c80);
    asm volatile("" : "+v"(woff0), "+v"(woff1));

    v8s bq[2][2];
    #pragma unroll
    for (int g = 0; g < 2; g++)
        #pragma unroll
        for (int hf = 0; hf < 2; hf++)
            bq[g][hf] = *(const v8s*)&Qg[(size_t)(g * 16 + u) * 64 + hf * 32 + quad * 8];

    v8s ones;
    #pragma unroll
    for (int i = 0; i < 8; i++) ones[i] = (short)0x3F80;

    v4f li4[2] = {};
    v4f O[4][2] = {};

    uint4 kr0 = *(const uint4*)&Kg[(size_t)row0 * 64 + c80 * 8];
    uint4 kr1 = *(const uint4*)&Kg[(size_t)row1 * 64 + c80 * 8];
    uint4 vr0 = *(const uint4*)&Vg[(size_t)row0 * MTOT + c80 * 8];
    uint4 vr1 = *(const uint4*)&Vg[(size_t)row1 * MTOT + c80 * 8];

    #pragma unroll 2
    for (int jc = 0; jc < NCH; jc++) {
        int cur = jc & 1;
        char* KbW = (char*)&Kbuf[cur][0];
        char* VbW = (char*)&Vbuf[cur][0];
        *(uint4*)(KbW + woff0) = kr0;
        *(uint4*)(KbW + woff1) = kr1;
        *(uint4*)(VbW + woff0) = vr0;
        *(uint4*)(VbW + woff1) = vr1;
        __syncthreads();
        if (jc + 1 < NCH) {
            int jb = (jc + 1) * 64;
            kr0 = *(const uint4*)&Kg[(size_t)(jb + row0) * 64 + c80 * 8];
            kr1 = *(const uint4*)&Kg[(size_t)(jb + row1) * 64 + c80 * 8];
            vr0 = *(const uint4*)&Vg[(size_t)row0 * MTOT + jb + c80 * 8];
            vr1 = *(const uint4*)&Vg[(size_t)row1 * MTOT + jb + c80 * 8];
        }

        const char* Kb = (const char*)&Kbuf[cur][0];
        const char* Vb = (const char*)&Vbuf[cur][0];

        v8s bp[2][2];
        #pragma unroll
        for (int kp = 0; kp < 2; kp++) {
            unsigned pk0[2][2], pk1[2][2];
            #pragma unroll
            for (int kk = 0; kk < 2; kk++) {
                int k4 = kp * 2 + kk;
                v8s ak0 = *(const v8s*)(Kb + boff[k4][0]);
                v8s ak1 = *(const v8s*)(Kb + boff[k4][1]);
                v4f st[2];
                __builtin_amdgcn_s_setprio(1);
                #pragma unroll
                for (int g = 0; g < 2; g++) {
                    st[g] = (v4f){0.f, 0.f, 0.f, 0.f};
                    st[g] = __builtin_amdgcn_mfma_f32_16x16x32_bf16(ak0, bq[g][0], st[g], 0, 0, 0);
                    st[g] = __builtin_amdgcn_mfma_f32_16x16x32_bf16(ak1, bq[g][1], st[g], 0, 0, 0);
                }
                __builtin_amdgcn_s_setprio(0);
                #pragma unroll
                for (int g = 0; g < 2; g++) {
                    float p0 = fexp2(st[g][0]);
                    float p1 = fexp2(st[g][1]);
                    float p2 = fexp2(st[g][2]);
                    float p3 = fexp2(st[g][3]);
                    pk0[g][kk] = pack2bf_t(p0, p1);
                    pk1[g][kk] = pack2bf_t(p2, p3);
                }
            }
            #pragma unroll
            for (int g = 0; g < 2; g++) {
                uint2v r0s = __builtin_amdgcn_permlane32_swap(pk0[g][0], pk0[g][1], false, false);
                uint2v r1s = __builtin_amdgcn_permlane32_swap(pk1[g][0], pk1[g][1], false, false);
                uint2v t0 = __builtin_amdgcn_permlane16_swap(r0s.x, r0s.y, false, false);
                uint2v t1 = __builtin_amdgcn_permlane16_swap(r1s.x, r1s.y, false, false);
                union { uint4 u4; v8s s; } cv;
                cv.u4.x = t0.x; cv.u4.y = t1.x; cv.u4.z = t0.y; cv.u4.w = t1.y;
                bp[g][kp] = cv.s;
            }
        }

        __builtin_amdgcn_s_setprio(1);
        #pragma unroll
        for (int g = 0; g < 2; g++) {
            li4[g] = __builtin_amdgcn_mfma_f32_16x16x32_bf16(ones, bp[g][0], li4[g], 0, 0, 0);
            li4[g] = __builtin_amdgcn_mfma_f32_16x16x32_bf16(ones, bp[g][1], li4[g], 0, 0, 0);
        }
        #pragma unroll
        for (int d4 = 0; d4 < 4; d4++) {
            v8s av0 = *(const v8s*)(Vb + boff[d4][0]);
            v8s av1 = *(const v8s*)(Vb + boff[d4][1]);
            #pragma unroll
            for (int g = 0; g < 2; g++) {
                O[d4][g] = __builtin_amdgcn_mfma_f32_16x16x32_bf16(av0, bp[g][0], O[d4][g], 0, 0, 0);
                O[d4][g] = __builtin_amdgcn_mfma_f32_16x16x32_bf16(av1, bp[g][1], O[d4][g], 0, 0, 0);
            }
        }
        __builtin_amdgcn_s_setprio(0);
    }

    #pragma unroll
    for (int g = 0; g < 2; g++) {
        int q = qb + g * 16 + u;
        size_t m2 = (size_t)(half * 2 + b) * 4096 + q;
        size_t base = m2 * 512 + h * 64;
        #pragma unroll
        for (int d4 = 0; d4 < 4; d4++) {
            uint2 o2;
            o2.x = pack2bf(O[d4][g][0], O[d4][g][1]);
            o2.y = pack2bf(O[d4][g][2], O[d4][g][3]);
            *(uint2*)&Opart[base + d4 * 16 + quad * 4] = o2;
        }
        if (quad == 0) liPart[m2 * 8 + h] = li4[g][0];
    }
}

// ---------------- combine the key-halves (bf16 partials) -> aoB bf16 [m][512] ----------------
__global__ __launch_bounds__(256) void k_comb(const ushortT* __restrict__ Opart,
                                              const float* __restrict__ liPart,
                                              ushortT* __restrict__ aoB) {
    int tid = blockIdx.x * 256 + threadIdx.x;
    int m = tid >> 7, c4 = (tid & 127) * 4, h = c4 >> 6;
    float l = 0.f;
    #pragma unroll
    for (int s = 0; s < NSPLIT; s++) l += liPart[((size_t)s * 8192 + m) * 8 + h];
    float inv = 1.f / l;
    float ox = 0.f, oy = 0.f, oz = 0.f, ow = 0.f;
    #pragma unroll
    for (int s = 0; s < NSPLIT; s++) {
        uint2 o = *(const uint2*)&Opart[((size_t)s * 8192 + m) * 512 + c4];
        ox += bflo(o.x); oy += bfhi(o.x);
        oz += bflo(o.y); ow += bfhi(o.y);
    }
    uint2 val;
    val.x = pack2bf(ox * inv, oy * inv);
    val.y = pack2bf(oz * inv, ow * inv);
    *(uint2*)&aoB[(size_t)m * 512 + c4] = val;
}

// ---------------- GEMM2 (bf16 MFMA): out = x + (wout*AO + bout)*alpha ----------------
__global__ __launch_bounds__(256) void k_gemm2(const ushortT* __restrict__ woutb, const ushortT* __restrict__ aoB,
                                               const float* __restrict__ bout, const float* __restrict__ x,
                                               const float* __restrict__ alpha, float* __restrict__ out) {
    __shared__ __align__(16) ushortT Al[64][40];
    __shared__ __align__(16) ushortT Bl[64][40];
    int mt = blockIdx.x * 64;
    int ot = blockIdx.y * 64;
    int t = threadIdx.x, w = t >> 6, lane = t & 63, u = lane & 15, quad = lane >> 4;
    int arow = t >> 2, ac8 = t & 3;
    v4f acc[4] = {};
    for (int k0 = 0; k0 < 512; k0 += 32) {
        __syncthreads();
        *(uint4*)&Al[arow][ac8 * 8] = *(const uint4*)&woutb[(size_t)(ot + arow) * 512 + k0 + ac8 * 8];
        *(uint4*)&Bl[arow][ac8 * 8] = *(const uint4*)&aoB[(size_t)(mt + arow) * 512 + k0 + ac8 * 8];
        __syncthreads();
        v8s a = *(v8s*)&Al[w * 16 + u][quad * 8];
        #pragma unroll
        for (int n4 = 0; n4 < 4; n4++) {
            v8s bb = *(v8s*)&Bl[n4 * 16 + u][quad * 8];
            acc[n4] = __builtin_amdgcn_mfma_f32_16x16x32_bf16(a, bb, acc[n4], 0, 0, 0);
        }
    }
    int b = mt >> 12, n0 = mt & 4095;
    int obase = ot + w * 16 + quad * 4;
    float bo[4];
    #pragma unroll
    for (int r = 0; r < 4; r++) bo[r] = bout[obase + r];
    #pragma unroll
    for (int n4 = 0; n4 < 4; n4++) {
        int n = n0 + n4 * 16 + u;
        float al = alpha[(size_t)b * NPOS + n];
        #pragma unroll
        for (int r = 0; r < 4; r++) {
            size_t xi = ((size_t)(b * 256 + obase + r)) * NPOS + n;
            out[xi] = x[xi] + (acc[n4][r] + bo[r]) * al;
        }
    }
}

extern "C" void kernel_launch(void* const* d_in, const int* in_sizes, int n_in,
                              void* d_out, int out_size, void* d_ws, size_t ws_size,
                              hipStream_t stream) {
    const float* x      = (const float*)d_in[0];
    const float* dsm    = (const float*)d_in[1];
    const float* wq     = (const float*)d_in[2];
    const float* wkv    = (const float*)d_in[3];
    const float* wout   = (const float*)d_in[4];
    const float* bout   = (const float*)d_in[5];
    const float* whape  = (const float*)d_in[6];
    const float* bhape  = (const float*)d_in[7];
    const float* walpha = (const float*)d_in[8];
    const float* balpha = (const float*)d_in[9];
    float* out = (float*)d_out;
    float* ws  = (float*)d_ws;

    size_t off = 0;
    float* alpha = ws + off; off += (size_t)2 * NPOS;
    float* biasc = ws + off; off += 2048;
    float* liPart = ws + off; off += (size_t)NSPLIT * MTOT * 8;
    ushortT* Opart = (ushortT*)(ws + off); off += (size_t)NSPLIT * MTOT * 512 / 2;
    ushortT* F     = (ushortT*)(ws + off); off += (size_t)MTOT * KP / 2;
    ushortT* Wc    = (ushortT*)(ws + off); off += (size_t)1536 * KP / 2;
    ushortT* woutb = (ushortT*)(ws + off); off += (size_t)256 * 512 / 2;
    ushortT* qT    = (ushortT*)(ws + off); off += (size_t)8 * MTOT * 64 / 2;
    ushortT* kT    = (ushortT*)(ws + off); off += (size_t)8 * MTOT * 64 / 2;
    ushortT* vv    = (ushortT*)(ws + off); off += (size_t)512 * MTOT / 2;
    ushortT* aoB   = (ushortT*)(ws + off); off += (size_t)MTOT * 512 / 2;
    (void)in_sizes; (void)n_in; (void)out_size; (void)ws_size;

    k_pre<<<2656, 256, 0, stream>>>(dsm, walpha, balpha, x, wq, wkv, whape, bhape, wout,
                                    F, alpha, Wc, biasc, woutb);
    k_gemm1<<<dim3(128, 6), 256, 0, stream>>>(Wc, F, biasc, qT, kT, vv);
    k_flash<<<dim3(32, 16, NSPLIT), 256, 0, stream>>>(qT, kT, vv, Opart, liPart);
    k_comb<<<4096, 256, 0, stream>>>(Opart, liPart, aoB);
    k_gemm2<<<dim3(128, 4), 256, 0, stream>>>(woutb, aoB, bout, x, alpha, out);
}

// Round 9
// 198.359 us; speedup vs baseline: 1.0426x; 1.0159x over previous
//
#include <hip/hip_runtime.h>
#include <math.h>

#define NPOS 4096   // H*W
#define MTOT 8192   // B*NPOS
#define KP   352    // padded feature dim (323 -> 352, mult of 32)
#define HT 64
#define WT 64
#define NSPLIT 2            // key-split factor for flash
#define KEYS_PER (NPOS / NSPLIT)   // 2048 keys per block
#define NCH (KEYS_PER / 64)        // 32 chunks

// F layout: cols 0..255 = x (bf16), 256..319 = PE [sin px, cos px, sin py, cos py],
//           320 = d, 321 = gx, 322 = gy, 323..351 = 0.  (Wc permuted to match.)

typedef unsigned short ushortT;
typedef short v8s __attribute__((ext_vector_type(8)));
typedef float v4f __attribute__((ext_vector_type(4)));
typedef unsigned uint2v __attribute__((ext_vector_type(2)));

static __device__ __forceinline__ ushortT bfr(float f) {
    union { float f; unsigned u; } v; v.f = f;
    return (ushortT)((v.u + 0x8000u) >> 16);
}
// round-half-up pack; low short = a
static __device__ __forceinline__ unsigned pack2bf(float a, float b) {
    union { float f; unsigned u; } ua, ub; ua.f = a; ub.f = b;
    return __builtin_amdgcn_perm(ub.u + 0x8000u, ua.u + 0x8000u, 0x07060302u);
}
// truncating pack (P values; softmax-safe)
static __device__ __forceinline__ unsigned pack2bf_t(float a, float b) {
    union { float f; unsigned u; } ua, ub; ua.f = a; ub.f = b;
    return __builtin_amdgcn_perm(ub.u, ua.u, 0x07060302u);
}
static __device__ __forceinline__ float fexp2(float x) {
#if __has_builtin(__builtin_amdgcn_exp2f)
    return __builtin_amdgcn_exp2f(x);
#else
    return exp2f(x);
#endif
}
static __device__ __forceinline__ float bflo(unsigned u) {
    union { unsigned u; float f; } v; v.u = u << 16; return v.f;
}
static __device__ __forceinline__ float bfhi(unsigned u) {
    union { unsigned u; float f; } v; v.u = u & 0xffff0000u; return v.f;
}

// ---------------- fused preprocessing: prep (32) | cast (512) | wcprep (2112) ----------------
__global__ void k_pre(const float* __restrict__ dsm,
                      const float* __restrict__ walpha, const float* __restrict__ balpha,
                      const float* __restrict__ x,
                      const float* __restrict__ wq, const float* __restrict__ wkv,
                      const float* __restrict__ whape, const float* __restrict__ bhape,
                      const float* __restrict__ wout,
                      ushortT* __restrict__ F, float* __restrict__ alpha,
                      ushortT* __restrict__ Wc, float* __restrict__ biasc,
                      ushortT* __restrict__ woutb) {
    __shared__ __align__(16) ushortT Tl[64][72];
    __shared__ float smn[4], smx[4];
    int role = blockIdx.x;
    int t = threadIdx.x;

    if (role < 32) {
        // ---- prep: d/gx/gy/PE -> F cols 256..351, alpha ----
        int idx = role * 256 + t;               // global m
        int b = idx / NPOS, n = idx % NPOS;
        int hh = n / WT, ww = n % WT;
        const float* dp = dsm + (size_t)b * NPOS;

        float mn = 1e30f, mx = -1e30f;
        for (int i = t; i < NPOS; i += 256) {
            float v = dp[i];
            mn = fminf(mn, v); mx = fmaxf(mx, v);
        }
        for (int off = 32; off; off >>= 1) {
            mn = fminf(mn, __shfl_xor(mn, off, 64));
            mx = fmaxf(mx, __shfl_xor(mx, off, 64));
        }
        int wid = t >> 6;
        if ((t & 63) == 0) { smn[wid] = mn; smx[wid] = mx; }
        __syncthreads();
        float dmin = fminf(fminf(smn[0], smn[1]), fminf(smn[2], smn[3]));
        float dmax = fmaxf(fmaxf(smx[0], smx[1]), fmaxf(smx[2], smx[3]));
        float inv = 1.0f / (dmax - dmin + 1e-6f);

        float dwin[5][5];
        #pragma unroll
        for (int dy = 0; dy < 5; dy++)
            #pragma unroll
            for (int dx = 0; dx < 5; dx++) {
                int y = hh + dy - 2, xx = ww + dx - 2;
                float v = 0.0f;
                if (y >= 0 && y < HT && xx >= 0 && xx < WT) v = (dp[y * WT + xx] - dmin) * inv;
                dwin[dy][dx] = v;
            }

        float gxc = 0.f, gyc = 0.f, conv = 0.f;
        #pragma unroll
        for (int oy = 0; oy < 3; oy++)
            #pragma unroll
            for (int ox = 0; ox < 3; ox++) {
                int qy = hh + oy - 1, qx = ww + ox - 1;
                float m = 0.0f;
                if (qy >= 0 && qy < HT && qx >= 0 && qx < WT) {
                    float gx = dwin[oy][ox] - dwin[oy][ox + 2]
                             + 2.f * dwin[oy + 1][ox] - 2.f * dwin[oy + 1][ox + 2]
                             + dwin[oy + 2][ox] - dwin[oy + 2][ox + 2];
                    float gy = dwin[oy][ox] + 2.f * dwin[oy][ox + 1] + dwin[oy][ox + 2]
                             - dwin[oy + 2][ox] - 2.f * dwin[oy + 2][ox + 1] - dwin[oy + 2][ox + 2];
                    if (oy == 1 && ox == 1) { gxc = gx; gyc = gy; }
                    float rx = fmaxf(gx, 0.f), ry = fmaxf(gy, 0.f);
                    m = sqrtf(rx * rx + ry * ry + 1e-12f);
                }
                conv += walpha[oy * 3 + ox] * m;
            }
        alpha[idx] = 1.f / (1.f + __expf(-(conv + balpha[0])));

        float xc = -1.f + 2.f * (float)ww / 63.f;
        float yc = -1.f + 2.f * (float)hh / 63.f;
        const float l2w = 13.287712379549449f;  // log2(10000)
        unsigned pe[32];
        #pragma unroll
        for (int i = 0; i < 16; i += 2) {
            float w0 = exp2f(-(float)i * (l2w / 16.f));
            float w1 = exp2f(-(float)(i + 1) * (l2w / 16.f));
            pe[i / 2]      = pack2bf(__sinf(xc * w0), __sinf(xc * w1));
            pe[8 + i / 2]  = pack2bf(__cosf(xc * w0), __cosf(xc * w1));
            pe[16 + i / 2] = pack2bf(__sinf(yc * w0), __sinf(yc * w1));
            pe[24 + i / 2] = pack2bf(__cosf(yc * w0), __cosf(yc * w1));
        }
        ushortT* fb = F + (size_t)idx * KP;
        uint4* dst = (uint4*)(fb + 256);
        #pragma unroll
        for (int q = 0; q < 8; q++) dst[q] = *(uint4*)&pe[q * 4];
        *(unsigned*)(fb + 320) = pack2bf(dwin[2][2], gxc);   // d, gx
        fb[322] = bfr(gyc);
        fb[323] = 0;
        *(unsigned*)(fb + 324) = 0;
        *(unsigned*)(fb + 326) = 0;
        uint4 z4 = {0, 0, 0, 0};
        *(uint4*)(fb + 328) = z4;
        *(uint4*)(fb + 336) = z4;
        *(uint4*)(fb + 344) = z4;
    } else if (role < 544) {
        // ---- cast: x -> F cols 0..255 (LDS transpose) ----
        int bid = role - 32;
        int nt = (bid & 63) * 64;
        int by = bid >> 6;
        int b = by >> 2, ct = (by & 3) * 64;
        #pragma unroll
        for (int rep = 0; rep < 4; rep++) {
            int row = rep * 16 + (t >> 4), c4 = (t & 15) * 4;
            float4 f4 = *(const float4*)&x[((size_t)(b * 256 + ct + row)) * NPOS + nt + c4];
            Tl[c4 + 0][row] = bfr(f4.x);
            Tl[c4 + 1][row] = bfr(f4.y);
            Tl[c4 + 2][row] = bfr(f4.z);
            Tl[c4 + 3][row] = bfr(f4.w);
        }
        __syncthreads();
        #pragma unroll
        for (int rep = 0; rep < 2; rep++) {
            int slot = rep * 256 + t, row = slot >> 3, c8 = slot & 7;
            *(uint4*)&F[((size_t)(b * 4096 + nt + row)) * KP + ct + c8 * 8] = *(uint4*)&Tl[row][c8 * 8];
        }
    } else {
        // ---- wcprep: combined weight Wc + biasc (+ wout cast) ----
        int bid = role - 544;
        int idx = bid * 256 + t;                // o*KP + k
        if (bid < 512) woutb[idx] = bfr(wout[idx]);
        int o = idx / KP, k = idx % KP;
        float v = 0.f;
        if (o < 512) {
            if (k < 256) v = wq[o * 256 + k] * 0.18033688011112042f;  // 0.125 * log2(e)
            if (k == 0) biasc[o] = 0.f;
        } else if (o < 1024) {
            int r = o - 512;
            if (k < 256) v = wkv[r * 257 + k];
            else if (k < 320) v = whape[r * 67 + (k - 256)];
            else if (k == 320) v = wkv[r * 257 + 256] + whape[r * 67 + 64];
            else if (k == 321) v = whape[r * 67 + 65];
            else if (k == 322) v = whape[r * 67 + 66];
            if (k == 0) biasc[o] = bhape[r];
        } else {
            int r = o - 512;
            if (k < 256) v = wkv[r * 257 + k];
            else if (k == 320) v = wkv[r * 257 + 256];
            if (k == 0) biasc[o] = 0.f;
        }
        Wc[idx] = bfr(v);
    }
}

// ---------------- GEMM1 (bf16 MFMA): 256x64 o-tiles, T14 register-prefetch pipeline ----------------
__global__ __launch_bounds__(256) void k_gemm1(const ushortT* __restrict__ Wc, const ushortT* __restrict__ F,
                                               const float* __restrict__ biasc,
                                               ushortT* __restrict__ qT, ushortT* __restrict__ kT,
                                               ushortT* __restrict__ vv) {
    __shared__ __align__(16) char smem[256 * 72 * 2];            // 36864 B
    ushortT (*Al)[40] = (ushortT(*)[40])smem;                    // 256 x 32 staged
    ushortT (*Bl)[40] = (ushortT(*)[40])(smem + 20480);          // 64 x 32 staged
    ushortT (*Vt)[72] = (ushortT(*)[72])smem;                    // alias: 256 x 64 transpose

    int mt = blockIdx.x * 64;
    int ot = blockIdx.y * 256;         // 0-1: q, 2-3: k, 4-5: v
    int t = threadIdx.x, w = t >> 6, lane = t & 63, u = lane & 15, quad = lane >> 4;
    int r4 = t >> 2, ch = t & 3;

    // T14 pipeline: prologue-load staging regs; per K-step {write LDS, barrier, issue next, compute, barrier}
    const ushortT* pA0 = Wc + (size_t)(ot +   0 + r4) * KP + ch * 8;
    const ushortT* pA1 = Wc + (size_t)(ot +  64 + r4) * KP + ch * 8;
    const ushortT* pA2 = Wc + (size_t)(ot + 128 + r4) * KP + ch * 8;
    const ushortT* pA3 = Wc + (size_t)(ot + 192 + r4) * KP + ch * 8;
    const ushortT* pB  = F  + (size_t)(mt + r4) * KP + ch * 8;
    uint4 ra0 = *(const uint4*)pA0;
    uint4 ra1 = *(const uint4*)pA1;
    uint4 ra2 = *(const uint4*)pA2;
    uint4 ra3 = *(const uint4*)pA3;
    uint4 rb  = *(const uint4*)pB;

    v4f acc[4][4] = {};
    for (int k0 = 0; k0 < KP; k0 += 32) {
        *(uint4*)&Al[  0 + r4][ch * 8] = ra0;
        *(uint4*)&Al[ 64 + r4][ch * 8] = ra1;
        *(uint4*)&Al[128 + r4][ch * 8] = ra2;
        *(uint4*)&Al[192 + r4][ch * 8] = ra3;
        *(uint4*)&Bl[r4][ch * 8] = rb;
        __syncthreads();
        if (k0 + 32 < KP) {   // issue next K-step's loads; latency hides under compute
            pA0 += 32; pA1 += 32; pA2 += 32; pA3 += 32; pB += 32;
            ra0 = *(const uint4*)pA0;
            ra1 = *(const uint4*)pA1;
            ra2 = *(const uint4*)pA2;
            ra3 = *(const uint4*)pA3;
            rb  = *(const uint4*)pB;
        }
        v8s a[4], bb[4];
        #pragma unroll
        for (int rr = 0; rr < 4; rr++) a[rr] = *(v8s*)&Al[w * 64 + rr * 16 + u][quad * 8];
        #pragma unroll
        for (int n4 = 0; n4 < 4; n4++) bb[n4] = *(v8s*)&Bl[n4 * 16 + u][quad * 8];
        #pragma unroll
        for (int rr = 0; rr < 4; rr++)
            #pragma unroll
            for (int n4 = 0; n4 < 4; n4++)
                acc[rr][n4] = __builtin_amdgcn_mfma_f32_16x16x32_bf16(a[rr], bb[n4], acc[rr][n4], 0, 0, 0);
        __syncthreads();   // all LDS reads done before next iteration's stores
    }
    float bo[4][4];
    #pragma unroll
    for (int rr = 0; rr < 4; rr++)
        #pragma unroll
        for (int r = 0; r < 4; r++) bo[rr][r] = biasc[ot + w * 64 + rr * 16 + quad * 4 + r];
    if (ot < 1024) {
        ushortT* dst = (ot < 512) ? qT : kT;
        #pragma unroll
        for (int rr = 0; rr < 4; rr++) {
            int oo = ot + w * 64 + rr * 16;
            int h = (oo >> 6) & 7;
            int dcol = (oo & 63) + quad * 4;
            #pragma unroll
            for (int n4 = 0; n4 < 4; n4++) {
                int m = mt + n4 * 16 + u;
                uint2 val;
                val.x = pack2bf(acc[rr][n4][0] + bo[rr][0], acc[rr][n4][1] + bo[rr][1]);
                val.y = pack2bf(acc[rr][n4][2] + bo[rr][2], acc[rr][n4][3] + bo[rr][3]);
                *(uint2*)&dst[((size_t)h * MTOT + m) * 64 + dcol] = val;
            }
        }
    } else {
        #pragma unroll
        for (int rr = 0; rr < 4; rr++)
            #pragma unroll
            for (int n4 = 0; n4 < 4; n4++) {
                int ml = n4 * 16 + u;
                #pragma unroll
                for (int r = 0; r < 4; r++)
                    Vt[w * 64 + rr * 16 + quad * 4 + r][ml] = bfr(acc[rr][n4][r] + bo[rr][r]);
            }
        __syncthreads();
        #pragma unroll
        for (int rep = 0; rep < 8; rep++) {
            int slot = rep * 256 + t, row = slot >> 3, c8 = slot & 7;
            *(uint4*)&vv[(size_t)(ot - 1024 + row) * MTOT + mt + c8 * 8] = *(uint4*)&Vt[row][c8 * 8];
        }
    }
}

// ---------------- flash attention (identical to passing R8 version) ----------------
#define LIDX(row, cb) (((row) << 6) + ((((cb) ^ ((row) & 7))) << 3))
__global__ __launch_bounds__(256, 4) void k_flash(const ushortT* __restrict__ qT,
                                                  const ushortT* __restrict__ kT,
                                                  const ushortT* __restrict__ vv,
                                                  ushortT* __restrict__ Opart,
                                                  float* __restrict__ liPart) {
    __shared__ __align__(16) ushortT Kbuf[2][64 * 64];
    __shared__ __align__(16) ushortT Vbuf[2][64 * 64];

    int it = blockIdx.x;
    int bh = blockIdx.y;
    int half = blockIdx.z;
    int b = bh >> 3, h = bh & 7;
    int colbase = b * NPOS;
    int t = threadIdx.x, w = t >> 6, lane = t & 63, u = lane & 15, quad = lane >> 4;
    int qb = it * 128 + w * 32;

    const ushortT* Qg = qT + ((size_t)h * MTOT + colbase + qb) * 64;
    const ushortT* Kg = kT + ((size_t)h * MTOT + colbase + half * KEYS_PER) * 64;
    const ushortT* Vg = vv + ((size_t)(h * 64)) * MTOT + colbase + half * KEYS_PER;

    int row0 = t >> 3, c80 = t & 7;
    int row1 = 32 + row0;

    unsigned boff[4][2];
    #pragma unroll
    for (int i4 = 0; i4 < 4; i4++) {
        boff[i4][0] = 2u * (unsigned)LIDX(i4 * 16 + u, quad);
        boff[i4][1] = 2u * (unsigned)LIDX(i4 * 16 + u, 4 + quad);
        asm volatile("" : "+v"(boff[i4][0]), "+v"(boff[i4][1]));
    }
    unsigned woff0 = 2u * (unsigned)LIDX(row0, c80);
    unsigned woff1 = 2u * (unsigned)LIDX(row1, c80);
    asm volatile("" : "+v"(woff0), "+v"(woff1));

    v8s bq[2][2];
    #pragma unroll
    for (int g = 0; g < 2; g++)
        #pragma unroll
        for (int hf = 0; hf < 2; hf++)
            bq[g][hf] = *(const v8s*)&Qg[(size_t)(g * 16 + u) * 64 + hf * 32 + quad * 8];

    v8s ones;
    #pragma unroll
    for (int i = 0; i < 8; i++) ones[i] = (short)0x3F80;

    v4f li4[2] = {};
    v4f O[4][2] = {};

    uint4 kr0 = *(const uint4*)&Kg[(size_t)row0 * 64 + c80 * 8];
    uint4 kr1 = *(const uint4*)&Kg[(size_t)row1 * 64 + c80 * 8];
    uint4 vr0 = *(const uint4*)&Vg[(size_t)row0 * MTOT + c80 * 8];
    uint4 vr1 = *(const uint4*)&Vg[(size_t)row1 * MTOT + c80 * 8];

    #pragma unroll 2
    for (int jc = 0; jc < NCH; jc++) {
        int cur = jc & 1;
        char* KbW = (char*)&Kbuf[cur][0];
        char* VbW = (char*)&Vbuf[cur][0];
        *(uint4*)(KbW + woff0) = kr0;
        *(uint4*)(KbW + woff1) = kr1;
        *(uint4*)(VbW + woff0) = vr0;
        *(uint4*)(VbW + woff1) = vr1;
        __syncthreads();
        if (jc + 1 < NCH) {
            int jb = (jc + 1) * 64;
            kr0 = *(const uint4*)&Kg[(size_t)(jb + row0) * 64 + c80 * 8];
            kr1 = *(const uint4*)&Kg[(size_t)(jb + row1) * 64 + c80 * 8];
            vr0 = *(const uint4*)&Vg[(size_t)row0 * MTOT + jb + c80 * 8];
            vr1 = *(const uint4*)&Vg[(size_t)row1 * MTOT + jb + c80 * 8];
        }

        const char* Kb = (const char*)&Kbuf[cur][0];
        const char* Vb = (const char*)&Vbuf[cur][0];

        v8s bp[2][2];
        #pragma unroll
        for (int kp = 0; kp < 2; kp++) {
            unsigned pk0[2][2], pk1[2][2];
            #pragma unroll
            for (int kk = 0; kk < 2; kk++) {
                int k4 = kp * 2 + kk;
                v8s ak0 = *(const v8s*)(Kb + boff[k4][0]);
                v8s ak1 = *(const v8s*)(Kb + boff[k4][1]);
                v4f st[2];
                __builtin_amdgcn_s_setprio(1);
                #pragma unroll
                for (int g = 0; g < 2; g++) {
                    st[g] = (v4f){0.f, 0.f, 0.f, 0.f};
                    st[g] = __builtin_amdgcn_mfma_f32_16x16x32_bf16(ak0, bq[g][0], st[g], 0, 0, 0);
                    st[g] = __builtin_amdgcn_mfma_f32_16x16x32_bf16(ak1, bq[g][1], st[g], 0, 0, 0);
                }
                __builtin_amdgcn_s_setprio(0);
                #pragma unroll
                for (int g = 0; g < 2; g++) {
                    float p0 = fexp2(st[g][0]);
                    float p1 = fexp2(st[g][1]);
                    float p2 = fexp2(st[g][2]);
                    float p3 = fexp2(st[g][3]);
                    pk0[g][kk] = pack2bf_t(p0, p1);
                    pk1[g][kk] = pack2bf_t(p2, p3);
                }
            }
            #pragma unroll
            for (int g = 0; g < 2; g++) {
                uint2v r0s = __builtin_amdgcn_permlane32_swap(pk0[g][0], pk0[g][1], false, false);
                uint2v r1s = __builtin_amdgcn_permlane32_swap(pk1[g][0], pk1[g][1], false, false);
                uint2v t0 = __builtin_amdgcn_permlane16_swap(r0s.x, r0s.y, false, false);
                uint2v t1 = __builtin_amdgcn_permlane16_swap(r1s.x, r1s.y, false, false);
                union { uint4 u4; v8s s; } cv;
                cv.u4.x = t0.x; cv.u4.y = t1.x; cv.u4.z = t0.y; cv.u4.w = t1.y;
                bp[g][kp] = cv.s;
            }
        }

        __builtin_amdgcn_s_setprio(1);
        #pragma unroll
        for (int g = 0; g < 2; g++) {
            li4[g] = __builtin_amdgcn_mfma_f32_16x16x32_bf16(ones, bp[g][0], li4[g], 0, 0, 0);
            li4[g] = __builtin_amdgcn_mfma_f32_16x16x32_bf16(ones, bp[g][1], li4[g], 0, 0, 0);
        }
        #pragma unroll
        for (int d4 = 0; d4 < 4; d4++) {
            v8s av0 = *(const v8s*)(Vb + boff[d4][0]);
            v8s av1 = *(const v8s*)(Vb + boff[d4][1]);
            #pragma unroll
            for (int g = 0; g < 2; g++) {
                O[d4][g] = __builtin_amdgcn_mfma_f32_16x16x32_bf16(av0, bp[g][0], O[d4][g], 0, 0, 0);
                O[d4][g] = __builtin_amdgcn_mfma_f32_16x16x32_bf16(av1, bp[g][1], O[d4][g], 0, 0, 0);
            }
        }
        __builtin_amdgcn_s_setprio(0);
    }

    #pragma unroll
    for (int g = 0; g < 2; g++) {
        int q = qb + g * 16 + u;
        size_t m2 = (size_t)(half * 2 + b) * 4096 + q;
        size_t base = m2 * 512 + h * 64;
        #pragma unroll
        for (int d4 = 0; d4 < 4; d4++) {
            uint2 o2;
            o2.x = pack2bf(O[d4][g][0], O[d4][g][1]);
            o2.y = pack2bf(O[d4][g][2], O[d4][g][3]);
            *(uint2*)&Opart[base + d4 * 16 + quad * 4] = o2;
        }
        if (quad == 0) liPart[m2 * 8 + h] = li4[g][0];
    }
}

// ---------------- GEMM2 + combine fused: out = x + (wout*(ΣOpart/Σli) + bout)*alpha ----------------
// o-tile 128 (grid 128x2); Bl staged by normalizing Opart halves inline (bit-identical to old comb).
__global__ __launch_bounds__(256) void k_gemm2(const ushortT* __restrict__ woutb,
                                               const ushortT* __restrict__ Opart,
                                               const float* __restrict__ liPart,
                                               const float* __restrict__ bout, const float* __restrict__ x,
                                               const float* __restrict__ alpha, float* __restrict__ out) {
    __shared__ __align__(16) ushortT Al[128][40];
    __shared__ __align__(16) ushortT Bl[64][40];
    int mt = blockIdx.x * 64;
    int ot = blockIdx.y * 128;
    int t = threadIdx.x, w = t >> 6, lane = t & 63, u = lane & 15, quad = lane >> 4;
    int r4 = t >> 2, ch = t & 3;
    int m = mt + r4;

    // per-thread m is fixed: precompute 1/li for all 8 heads (li reads are L2-resident)
    float linv[8];
    #pragma unroll
    for (int h = 0; h < 8; h++)
        linv[h] = 1.f / (liPart[(size_t)m * 8 + h] + liPart[(size_t)(8192 + m) * 8 + h]);

    const ushortT* pA0 = woutb + (size_t)(ot + r4) * 512 + ch * 8;
    const ushortT* pA1 = woutb + (size_t)(ot + 64 + r4) * 512 + ch * 8;
    const ushortT* pO0 = Opart + (size_t)m * 512 + ch * 8;
    const ushortT* pO1 = Opart + (size_t)(8192 + m) * 512 + ch * 8;
    uint4 ra0 = *(const uint4*)pA0;
    uint4 ra1 = *(const uint4*)pA1;
    uint4 ro0 = *(const uint4*)pO0;
    uint4 ro1 = *(const uint4*)pO1;

    v4f acc[2][4] = {};
    for (int k0 = 0; k0 < 512; k0 += 32) {
        // inline combine: (o_half0 + o_half1) * inv  -> bf16 (same expression as old k_comb)
        int h = (k0 + ch * 8) >> 6;    // 8-aligned block never crosses a head boundary
        float iv = linv[h];
        uint4 bv;
        bv.x = pack2bf((bflo(ro0.x) + bflo(ro1.x)) * iv, (bfhi(ro0.x) + bfhi(ro1.x)) * iv);
        bv.y = pack2bf((bflo(ro0.y) + bflo(ro1.y)) * iv, (bfhi(ro0.y) + bfhi(ro1.y)) * iv);
        bv.z = pack2bf((bflo(ro0.z) + bflo(ro1.z)) * iv, (bfhi(ro0.z) + bfhi(ro1.z)) * iv);
        bv.w = pack2bf((bflo(ro0.w) + bflo(ro1.w)) * iv, (bfhi(ro0.w) + bfhi(ro1.w)) * iv);
        *(uint4*)&Al[r4][ch * 8] = ra0;
        *(uint4*)&Al[64 + r4][ch * 8] = ra1;
        *(uint4*)&Bl[r4][ch * 8] = bv;
        __syncthreads();
        if (k0 + 32 < 512) {   // issue next K-step's loads
            pA0 += 32; pA1 += 32; pO0 += 32; pO1 += 32;
            ra0 = *(const uint4*)pA0;
            ra1 = *(const uint4*)pA1;
            ro0 = *(const uint4*)pO0;
            ro1 = *(const uint4*)pO1;
        }
        v8s a[2], bb[4];
        #pragma unroll
        for (int rr = 0; rr < 2; rr++) a[rr] = *(v8s*)&Al[w * 32 + rr * 16 + u][quad * 8];
        #pragma unroll
        for (int n4 = 0; n4 < 4; n4++) bb[n4] = *(v8s*)&Bl[n4 * 16 + u][quad * 8];
        #pragma unroll
        for (int rr = 0; rr < 2; rr++)
            #pragma unroll
            for (int n4 = 0; n4 < 4; n4++)
                acc[rr][n4] = __builtin_amdgcn_mfma_f32_16x16x32_bf16(a[rr], bb[n4], acc[rr][n4], 0, 0, 0);
        __syncthreads();
    }
    int b = mt >> 12, n0 = mt & 4095;
    #pragma unroll
    for (int rr = 0; rr < 2; rr++) {
        int obase = ot + w * 32 + rr * 16 + quad * 4;
        float bo[4];
        #pragma unroll
        for (int r = 0; r < 4; r++) bo[r] = bout[obase + r];
        #pragma unroll
        for (int n4 = 0; n4 < 4; n4++) {
            int n = n0 + n4 * 16 + u;
            float al = alpha[(size_t)b * NPOS + n];
            #pragma unroll
            for (int r = 0; r < 4; r++) {
                size_t xi = ((size_t)(b * 256 + obase + r)) * NPOS + n;
                out[xi] = x[xi] + (acc[rr][n4][r] + bo[r]) * al;
            }
        }
    }
}

extern "C" void kernel_launch(void* const* d_in, const int* in_sizes, int n_in,
                              void* d_out, int out_size, void* d_ws, size_t ws_size,
                              hipStream_t stream) {
    const float* x      = (const float*)d_in[0];
    const float* dsm    = (const float*)d_in[1];
    const float* wq     = (const float*)d_in[2];
    const float* wkv    = (const float*)d_in[3];
    const float* wout   = (const float*)d_in[4];
    const float* bout   = (const float*)d_in[5];
    const float* whape  = (const float*)d_in[6];
    const float* bhape  = (const float*)d_in[7];
    const float* walpha = (const float*)d_in[8];
    const float* balpha = (const float*)d_in[9];
    float* out = (float*)d_out;
    float* ws  = (float*)d_ws;

    size_t off = 0;
    float* alpha = ws + off; off += (size_t)2 * NPOS;
    float* biasc = ws + off; off += 2048;
    float* liPart = ws + off; off += (size_t)NSPLIT * MTOT * 8;
    ushortT* Opart = (ushortT*)(ws + off); off += (size_t)NSPLIT * MTOT * 512 / 2;
    ushortT* F     = (ushortT*)(ws + off); off += (size_t)MTOT * KP / 2;
    ushortT* Wc    = (ushortT*)(ws + off); off += (size_t)1536 * KP / 2;
    ushortT* woutb = (ushortT*)(ws + off); off += (size_t)256 * 512 / 2;
    ushortT* qT    = (ushortT*)(ws + off); off += (size_t)8 * MTOT * 64 / 2;
    ushortT* kT    = (ushortT*)(ws + off); off += (size_t)8 * MTOT * 64 / 2;
    ushortT* vv    = (ushortT*)(ws + off); off += (size_t)512 * MTOT / 2;
    (void)in_sizes; (void)n_in; (void)out_size; (void)ws_size;

    k_pre<<<2656, 256, 0, stream>>>(dsm, walpha, balpha, x, wq, wkv, whape, bhape, wout,
                                    F, alpha, Wc, biasc, woutb);
    k_gemm1<<<dim3(128, 6), 256, 0, stream>>>(Wc, F, biasc, qT, kT, vv);
    k_flash<<<dim3(32, 16, NSPLIT), 256, 0, stream>>>(qT, kT, vv, Opart, liPart);
    k_gemm2<<<dim3(128, 2), 256, 0, stream>>>(woutb, Opart, liPart, bout, x, alpha, out);
}

// Round 10
// 196.339 us; speedup vs baseline: 1.0534x; 1.0103x over previous
//
#include <hip/hip_runtime.h>
#include <math.h>

#define NPOS 4096   // H*W
#define MTOT 8192   // B*NPOS
#define KP   352    // padded feature dim (323 -> 352, mult of 32)
#define HT 64
#define WT 64
#define NSPLIT 2            // key-split factor for flash
#define KEYS_PER (NPOS / NSPLIT)   // 2048 keys per block
#define NCH (KEYS_PER / 64)        // 32 chunks

// F layout: cols 0..255 = x (bf16), 256..319 = PE [sin px, cos px, sin py, cos py],
//           320 = d, 321 = gx, 322 = gy, 323..351 = 0.  (Wc permuted to match.)

typedef unsigned short ushortT;
typedef short v8s __attribute__((ext_vector_type(8)));
typedef float v4f __attribute__((ext_vector_type(4)));
typedef unsigned uint2v __attribute__((ext_vector_type(2)));

static __device__ __forceinline__ ushortT bfr(float f) {
    union { float f; unsigned u; } v; v.f = f;
    return (ushortT)((v.u + 0x8000u) >> 16);
}
// round-half-up pack; low short = a
static __device__ __forceinline__ unsigned pack2bf(float a, float b) {
    union { float f; unsigned u; } ua, ub; ua.f = a; ub.f = b;
    return __builtin_amdgcn_perm(ub.u + 0x8000u, ua.u + 0x8000u, 0x07060302u);
}
// truncating pack (P values; softmax-safe)
static __device__ __forceinline__ unsigned pack2bf_t(float a, float b) {
    union { float f; unsigned u; } ua, ub; ua.f = a; ub.f = b;
    return __builtin_amdgcn_perm(ub.u, ua.u, 0x07060302u);
}
static __device__ __forceinline__ float fexp2(float x) {
#if __has_builtin(__builtin_amdgcn_exp2f)
    return __builtin_amdgcn_exp2f(x);
#else
    return exp2f(x);
#endif
}
static __device__ __forceinline__ float bflo(unsigned u) {
    union { unsigned u; float f; } v; v.u = u << 16; return v.f;
}
static __device__ __forceinline__ float bfhi(unsigned u) {
    union { unsigned u; float f; } v; v.u = u & 0xffff0000u; return v.f;
}

// ---------------- fused preprocessing: prep (32) | cast (512) | wcprep (2112) ----------------
__global__ void k_pre(const float* __restrict__ dsm,
                      const float* __restrict__ walpha, const float* __restrict__ balpha,
                      const float* __restrict__ x,
                      const float* __restrict__ wq, const float* __restrict__ wkv,
                      const float* __restrict__ whape, const float* __restrict__ bhape,
                      const float* __restrict__ wout,
                      ushortT* __restrict__ F, float* __restrict__ alpha,
                      ushortT* __restrict__ Wc, float* __restrict__ biasc,
                      ushortT* __restrict__ woutb) {
    __shared__ __align__(16) ushortT Tl[64][72];
    __shared__ float smn[4], smx[4];
    int role = blockIdx.x;
    int t = threadIdx.x;

    if (role < 32) {
        // ---- prep: d/gx/gy/PE -> F cols 256..351, alpha ----
        int idx = role * 256 + t;               // global m
        int b = idx / NPOS, n = idx % NPOS;
        int hh = n / WT, ww = n % WT;
        const float* dp = dsm + (size_t)b * NPOS;

        float mn = 1e30f, mx = -1e30f;
        for (int i = t; i < NPOS; i += 256) {
            float v = dp[i];
            mn = fminf(mn, v); mx = fmaxf(mx, v);
        }
        for (int off = 32; off; off >>= 1) {
            mn = fminf(mn, __shfl_xor(mn, off, 64));
            mx = fmaxf(mx, __shfl_xor(mx, off, 64));
        }
        int wid = t >> 6;
        if ((t & 63) == 0) { smn[wid] = mn; smx[wid] = mx; }
        __syncthreads();
        float dmin = fminf(fminf(smn[0], smn[1]), fminf(smn[2], smn[3]));
        float dmax = fmaxf(fmaxf(smx[0], smx[1]), fmaxf(smx[2], smx[3]));
        float inv = 1.0f / (dmax - dmin + 1e-6f);

        float dwin[5][5];
        #pragma unroll
        for (int dy = 0; dy < 5; dy++)
            #pragma unroll
            for (int dx = 0; dx < 5; dx++) {
                int y = hh + dy - 2, xx = ww + dx - 2;
                float v = 0.0f;
                if (y >= 0 && y < HT && xx >= 0 && xx < WT) v = (dp[y * WT + xx] - dmin) * inv;
                dwin[dy][dx] = v;
            }

        float gxc = 0.f, gyc = 0.f, conv = 0.f;
        #pragma unroll
        for (int oy = 0; oy < 3; oy++)
            #pragma unroll
            for (int ox = 0; ox < 3; ox++) {
                int qy = hh + oy - 1, qx = ww + ox - 1;
                float m = 0.0f;
                if (qy >= 0 && qy < HT && qx >= 0 && qx < WT) {
                    float gx = dwin[oy][ox] - dwin[oy][ox + 2]
                             + 2.f * dwin[oy + 1][ox] - 2.f * dwin[oy + 1][ox + 2]
                             + dwin[oy + 2][ox] - dwin[oy + 2][ox + 2];
                    float gy = dwin[oy][ox] + 2.f * dwin[oy][ox + 1] + dwin[oy][ox + 2]
                             - dwin[oy + 2][ox] - 2.f * dwin[oy + 2][ox + 1] - dwin[oy + 2][ox + 2];
                    if (oy == 1 && ox == 1) { gxc = gx; gyc = gy; }
                    float rx = fmaxf(gx, 0.f), ry = fmaxf(gy, 0.f);
                    m = sqrtf(rx * rx + ry * ry + 1e-12f);
                }
                conv += walpha[oy * 3 + ox] * m;
            }
        alpha[idx] = 1.f / (1.f + __expf(-(conv + balpha[0])));

        float xc = -1.f + 2.f * (float)ww / 63.f;
        float yc = -1.f + 2.f * (float)hh / 63.f;
        const float l2w = 13.287712379549449f;  // log2(10000)
        unsigned pe[32];
        #pragma unroll
        for (int i = 0; i < 16; i += 2) {
            float w0 = exp2f(-(float)i * (l2w / 16.f));
            float w1 = exp2f(-(float)(i + 1) * (l2w / 16.f));
            pe[i / 2]      = pack2bf(__sinf(xc * w0), __sinf(xc * w1));
            pe[8 + i / 2]  = pack2bf(__cosf(xc * w0), __cosf(xc * w1));
            pe[16 + i / 2] = pack2bf(__sinf(yc * w0), __sinf(yc * w1));
            pe[24 + i / 2] = pack2bf(__cosf(yc * w0), __cosf(yc * w1));
        }
        ushortT* fb = F + (size_t)idx * KP;
        uint4* dst = (uint4*)(fb + 256);
        #pragma unroll
        for (int q = 0; q < 8; q++) dst[q] = *(uint4*)&pe[q * 4];
        *(unsigned*)(fb + 320) = pack2bf(dwin[2][2], gxc);   // d, gx
        fb[322] = bfr(gyc);
        fb[323] = 0;
        *(unsigned*)(fb + 324) = 0;
        *(unsigned*)(fb + 326) = 0;
        uint4 z4 = {0, 0, 0, 0};
        *(uint4*)(fb + 328) = z4;
        *(uint4*)(fb + 336) = z4;
        *(uint4*)(fb + 344) = z4;
    } else if (role < 544) {
        // ---- cast: x -> F cols 0..255 (LDS transpose) ----
        int bid = role - 32;
        int nt = (bid & 63) * 64;
        int by = bid >> 6;
        int b = by >> 2, ct = (by & 3) * 64;
        #pragma unroll
        for (int rep = 0; rep < 4; rep++) {
            int row = rep * 16 + (t >> 4), c4 = (t & 15) * 4;
            float4 f4 = *(const float4*)&x[((size_t)(b * 256 + ct + row)) * NPOS + nt + c4];
            Tl[c4 + 0][row] = bfr(f4.x);
            Tl[c4 + 1][row] = bfr(f4.y);
            Tl[c4 + 2][row] = bfr(f4.z);
            Tl[c4 + 3][row] = bfr(f4.w);
        }
        __syncthreads();
        #pragma unroll
        for (int rep = 0; rep < 2; rep++) {
            int slot = rep * 256 + t, row = slot >> 3, c8 = slot & 7;
            *(uint4*)&F[((size_t)(b * 4096 + nt + row)) * KP + ct + c8 * 8] = *(uint4*)&Tl[row][c8 * 8];
        }
    } else {
        // ---- wcprep: combined weight Wc + biasc (+ wout cast) ----
        int bid = role - 544;
        int idx = bid * 256 + t;                // o*KP + k
        if (bid < 512) woutb[idx] = bfr(wout[idx]);
        int o = idx / KP, k = idx % KP;
        float v = 0.f;
        if (o < 512) {
            if (k < 256) v = wq[o * 256 + k] * 0.18033688011112042f;  // 0.125 * log2(e)
            if (k == 0) biasc[o] = 0.f;
        } else if (o < 1024) {
            int r = o - 512;
            if (k < 256) v = wkv[r * 257 + k];
            else if (k < 320) v = whape[r * 67 + (k - 256)];
            else if (k == 320) v = wkv[r * 257 + 256] + whape[r * 67 + 64];
            else if (k == 321) v = whape[r * 67 + 65];
            else if (k == 322) v = whape[r * 67 + 66];
            if (k == 0) biasc[o] = bhape[r];
        } else {
            int r = o - 512;
            if (k < 256) v = wkv[r * 257 + k];
            else if (k == 320) v = wkv[r * 257 + 256];
            if (k == 0) biasc[o] = 0.f;
        }
        Wc[idx] = bfr(v);
    }
}

// ---------------- GEMM1: 256x64 o-tiles, T14 pipeline, XCD-packed (same-mt blocks per XCD) ----------------
__global__ __launch_bounds__(256) void k_gemm1(const ushortT* __restrict__ Wc, const ushortT* __restrict__ F,
                                               const float* __restrict__ biasc,
                                               ushortT* __restrict__ qT, ushortT* __restrict__ kT,
                                               ushortT* __restrict__ vv) {
    __shared__ __align__(16) char smem[256 * 72 * 2];            // 36864 B
    ushortT (*Al)[40] = (ushortT(*)[40])smem;                    // 256 x 32 staged
    ushortT (*Bl)[40] = (ushortT(*)[40])(smem + 20480);          // 64 x 32 staged
    ushortT (*Vt)[72] = (ushortT(*)[72])smem;                    // alias: 256 x 64 transpose

    // bijective XCD swizzle: 768 = 8 xcd x 16 xhi x 6 y; all 6 y-blocks of one mt share an XCD
    int fid = blockIdx.x;
    int xcd = fid & 7;
    int rr_ = fid >> 3;          // 0..95
    int yt = rr_ % 6;
    int xt = xcd + 8 * (rr_ / 6);   // 0..127
    int mt = xt * 64;
    int ot = yt * 256;           // 0-1: q, 2-3: k, 4-5: v

    int t = threadIdx.x, w = t >> 6, lane = t & 63, u = lane & 15, quad = lane >> 4;
    int r4 = t >> 2, ch = t & 3;

    const ushortT* pA0 = Wc + (size_t)(ot +   0 + r4) * KP + ch * 8;
    const ushortT* pA1 = Wc + (size_t)(ot +  64 + r4) * KP + ch * 8;
    const ushortT* pA2 = Wc + (size_t)(ot + 128 + r4) * KP + ch * 8;
    const ushortT* pA3 = Wc + (size_t)(ot + 192 + r4) * KP + ch * 8;
    const ushortT* pB  = F  + (size_t)(mt + r4) * KP + ch * 8;
    uint4 ra0 = *(const uint4*)pA0;
    uint4 ra1 = *(const uint4*)pA1;
    uint4 ra2 = *(const uint4*)pA2;
    uint4 ra3 = *(const uint4*)pA3;
    uint4 rb  = *(const uint4*)pB;

    v4f acc[4][4] = {};
    for (int k0 = 0; k0 < KP; k0 += 32) {
        *(uint4*)&Al[  0 + r4][ch * 8] = ra0;
        *(uint4*)&Al[ 64 + r4][ch * 8] = ra1;
        *(uint4*)&Al[128 + r4][ch * 8] = ra2;
        *(uint4*)&Al[192 + r4][ch * 8] = ra3;
        *(uint4*)&Bl[r4][ch * 8] = rb;
        __syncthreads();
        if (k0 + 32 < KP) {
            pA0 += 32; pA1 += 32; pA2 += 32; pA3 += 32; pB += 32;
            ra0 = *(const uint4*)pA0;
            ra1 = *(const uint4*)pA1;
            ra2 = *(const uint4*)pA2;
            ra3 = *(const uint4*)pA3;
            rb  = *(const uint4*)pB;
        }
        v8s a[4], bb[4];
        #pragma unroll
        for (int rr = 0; rr < 4; rr++) a[rr] = *(v8s*)&Al[w * 64 + rr * 16 + u][quad * 8];
        #pragma unroll
        for (int n4 = 0; n4 < 4; n4++) bb[n4] = *(v8s*)&Bl[n4 * 16 + u][quad * 8];
        #pragma unroll
        for (int rr = 0; rr < 4; rr++)
            #pragma unroll
            for (int n4 = 0; n4 < 4; n4++)
                acc[rr][n4] = __builtin_amdgcn_mfma_f32_16x16x32_bf16(a[rr], bb[n4], acc[rr][n4], 0, 0, 0);
        __syncthreads();
    }
    float bo[4][4];
    #pragma unroll
    for (int rr = 0; rr < 4; rr++)
        #pragma unroll
        for (int r = 0; r < 4; r++) bo[rr][r] = biasc[ot + w * 64 + rr * 16 + quad * 4 + r];
    if (ot < 1024) {
        ushortT* dst = (ot < 512) ? qT : kT;
        #pragma unroll
        for (int rr = 0; rr < 4; rr++) {
            int oo = ot + w * 64 + rr * 16;
            int h = (oo >> 6) & 7;
            int dcol = (oo & 63) + quad * 4;
            #pragma unroll
            for (int n4 = 0; n4 < 4; n4++) {
                int m = mt + n4 * 16 + u;
                uint2 val;
                val.x = pack2bf(acc[rr][n4][0] + bo[rr][0], acc[rr][n4][1] + bo[rr][1]);
                val.y = pack2bf(acc[rr][n4][2] + bo[rr][2], acc[rr][n4][3] + bo[rr][3]);
                *(uint2*)&dst[((size_t)h * MTOT + m) * 64 + dcol] = val;
            }
        }
    } else {
        #pragma unroll
        for (int rr = 0; rr < 4; rr++)
            #pragma unroll
            for (int n4 = 0; n4 < 4; n4++) {
                int ml = n4 * 16 + u;
                #pragma unroll
                for (int r = 0; r < 4; r++)
                    Vt[w * 64 + rr * 16 + quad * 4 + r][ml] = bfr(acc[rr][n4][r] + bo[rr][r]);
            }
        __syncthreads();
        #pragma unroll
        for (int rep = 0; rep < 8; rep++) {
            int slot = rep * 256 + t, row = slot >> 3, c8 = slot & 7;
            *(uint4*)&vv[(size_t)(ot - 1024 + row) * MTOT + mt + c8 * 8] = *(uint4*)&Vt[row][c8 * 8];
        }
    }
}

// ---------------- flash attention: XCD-packed (same (bh,half) K/V combo per XCD) ----------------
#define LIDX(row, cb) (((row) << 6) + ((((cb) ^ ((row) & 7))) << 3))
__global__ __launch_bounds__(256, 4) void k_flash(const ushortT* __restrict__ qT,
                                                  const ushortT* __restrict__ kT,
                                                  const ushortT* __restrict__ vv,
                                                  ushortT* __restrict__ Opart,
                                                  float* __restrict__ liPart) {
    __shared__ __align__(16) ushortT Kbuf[2][64 * 64];
    __shared__ __align__(16) ushortT Vbuf[2][64 * 64];

    // bijective XCD swizzle: 1024 = 8 xcd x 32 it x 4 chi; combo c = xcd + 8*chi (0..31)
    // -> all 32 it-blocks of one (bh,half) land on one XCD (K/V half = 512 KB L2-resident)
    int fid = blockIdx.x;
    int xcd = fid & 7;
    int rr_ = fid >> 3;          // 0..127
    int it = rr_ & 31;
    int chi = rr_ >> 5;          // 0..3
    int c = xcd + 8 * chi;       // 0..31
    int bh = c & 15;
    int half = c >> 4;

    int b = bh >> 3, h = bh & 7;
    int colbase = b * NPOS;
    int t = threadIdx.x, w = t >> 6, lane = t & 63, u = lane & 15, quad = lane >> 4;
    int qb = it * 128 + w * 32;

    const ushortT* Qg = qT + ((size_t)h * MTOT + colbase + qb) * 64;
    const ushortT* Kg = kT + ((size_t)h * MTOT + colbase + half * KEYS_PER) * 64;
    const ushortT* Vg = vv + ((size_t)(h * 64)) * MTOT + colbase + half * KEYS_PER;

    int row0 = t >> 3, c80 = t & 7;
    int row1 = 32 + row0;

    unsigned boff[4][2];
    #pragma unroll
    for (int i4 = 0; i4 < 4; i4++) {
        boff[i4][0] = 2u * (unsigned)LIDX(i4 * 16 + u, quad);
        boff[i4][1] = 2u * (unsigned)LIDX(i4 * 16 + u, 4 + quad);
        asm volatile("" : "+v"(boff[i4][0]), "+v"(boff[i4][1]));
    }
    unsigned woff0 = 2u * (unsigned)LIDX(row0, c80);
    unsigned woff1 = 2u * (unsigned)LIDX(row1, c80);
    asm volatile("" : "+v"(woff0), "+v"(woff1));

    v8s bq[2][2];
    #pragma unroll
    for (int g = 0; g < 2; g++)
        #pragma unroll
        for (int hf = 0; hf < 2; hf++)
            bq[g][hf] = *(const v8s*)&Qg[(size_t)(g * 16 + u) * 64 + hf * 32 + quad * 8];

    v8s ones;
    #pragma unroll
    for (int i = 0; i < 8; i++) ones[i] = (short)0x3F80;

    v4f li4[2] = {};
    v4f O[4][2] = {};

    uint4 kr0 = *(const uint4*)&Kg[(size_t)row0 * 64 + c80 * 8];
    uint4 kr1 = *(const uint4*)&Kg[(size_t)row1 * 64 + c80 * 8];
    uint4 vr0 = *(const uint4*)&Vg[(size_t)row0 * MTOT + c80 * 8];
    uint4 vr1 = *(const uint4*)&Vg[(size_t)row1 * MTOT + c80 * 8];

    #pragma unroll 2
    for (int jc = 0; jc < NCH; jc++) {
        int cur = jc & 1;
        char* KbW = (char*)&Kbuf[cur][0];
        char* VbW = (char*)&Vbuf[cur][0];
        *(uint4*)(KbW + woff0) = kr0;
        *(uint4*)(KbW + woff1) = kr1;
        *(uint4*)(VbW + woff0) = vr0;
        *(uint4*)(VbW + woff1) = vr1;
        __syncthreads();
        if (jc + 1 < NCH) {
            int jb = (jc + 1) * 64;
            kr0 = *(const uint4*)&Kg[(size_t)(jb + row0) * 64 + c80 * 8];
            kr1 = *(const uint4*)&Kg[(size_t)(jb + row1) * 64 + c80 * 8];
            vr0 = *(const uint4*)&Vg[(size_t)row0 * MTOT + jb + c80 * 8];
            vr1 = *(const uint4*)&Vg[(size_t)row1 * MTOT + jb + c80 * 8];
        }

        const char* Kb = (const char*)&Kbuf[cur][0];
        const char* Vb = (const char*)&Vbuf[cur][0];

        v8s bp[2][2];
        #pragma unroll
        for (int kp = 0; kp < 2; kp++) {
            unsigned pk0[2][2], pk1[2][2];
            #pragma unroll
            for (int kk = 0; kk < 2; kk++) {
                int k4 = kp * 2 + kk;
                v8s ak0 = *(const v8s*)(Kb + boff[k4][0]);
                v8s ak1 = *(const v8s*)(Kb + boff[k4][1]);
                v4f st[2];
                __builtin_amdgcn_s_setprio(1);
                #pragma unroll
                for (int g = 0; g < 2; g++) {
                    st[g] = (v4f){0.f, 0.f, 0.f, 0.f};
                    st[g] = __builtin_amdgcn_mfma_f32_16x16x32_bf16(ak0, bq[g][0], st[g], 0, 0, 0);
                    st[g] = __builtin_amdgcn_mfma_f32_16x16x32_bf16(ak1, bq[g][1], st[g], 0, 0, 0);
                }
                __builtin_amdgcn_s_setprio(0);
                #pragma unroll
                for (int g = 0; g < 2; g++) {
                    float p0 = fexp2(st[g][0]);
                    float p1 = fexp2(st[g][1]);
                    float p2 = fexp2(st[g][2]);
                    float p3 = fexp2(st[g][3]);
                    pk0[g][kk] = pack2bf_t(p0, p1);
                    pk1[g][kk] = pack2bf_t(p2, p3);
                }
            }
            #pragma unroll
            for (int g = 0; g < 2; g++) {
                uint2v r0s = __builtin_amdgcn_permlane32_swap(pk0[g][0], pk0[g][1], false, false);
                uint2v r1s = __builtin_amdgcn_permlane32_swap(pk1[g][0], pk1[g][1], false, false);
                uint2v t0 = __builtin_amdgcn_permlane16_swap(r0s.x, r0s.y, false, false);
                uint2v t1 = __builtin_amdgcn_permlane16_swap(r1s.x, r1s.y, false, false);
                union { uint4 u4; v8s s; } cv;
                cv.u4.x = t0.x; cv.u4.y = t1.x; cv.u4.z = t0.y; cv.u4.w = t1.y;
                bp[g][kp] = cv.s;
            }
        }

        __builtin_amdgcn_s_setprio(1);
        #pragma unroll
        for (int g = 0; g < 2; g++) {
            li4[g] = __builtin_amdgcn_mfma_f32_16x16x32_bf16(ones, bp[g][0], li4[g], 0, 0, 0);
            li4[g] = __builtin_amdgcn_mfma_f32_16x16x32_bf16(ones, bp[g][1], li4[g], 0, 0, 0);
        }
        #pragma unroll
        for (int d4 = 0; d4 < 4; d4++) {
            v8s av0 = *(const v8s*)(Vb + boff[d4][0]);
            v8s av1 = *(const v8s*)(Vb + boff[d4][1]);
            #pragma unroll
            for (int g = 0; g < 2; g++) {
                O[d4][g] = __builtin_amdgcn_mfma_f32_16x16x32_bf16(av0, bp[g][0], O[d4][g], 0, 0, 0);
                O[d4][g] = __builtin_amdgcn_mfma_f32_16x16x32_bf16(av1, bp[g][1], O[d4][g], 0, 0, 0);
            }
        }
        __builtin_amdgcn_s_setprio(0);
    }

    #pragma unroll
    for (int g = 0; g < 2; g++) {
        int q = qb + g * 16 + u;
        size_t m2 = (size_t)(half * 2 + b) * 4096 + q;
        size_t base = m2 * 512 + h * 64;
        #pragma unroll
        for (int d4 = 0; d4 < 4; d4++) {
            uint2 o2;
            o2.x = pack2bf(O[d4][g][0], O[d4][g][1]);
            o2.y = pack2bf(O[d4][g][2], O[d4][g][3]);
            *(uint2*)&Opart[base + d4 * 16 + quad * 4] = o2;
        }
        if (quad == 0) liPart[m2 * 8 + h] = li4[g][0];
    }
}

// ---------------- GEMM2 + combine fused: BM=32 (grid 256x2 -> 2 blocks/CU) ----------------
__global__ __launch_bounds__(256) void k_gemm2(const ushortT* __restrict__ woutb,
                                               const ushortT* __restrict__ Opart,
                                               const float* __restrict__ liPart,
                                               const float* __restrict__ bout, const float* __restrict__ x,
                                               const float* __restrict__ alpha, float* __restrict__ out) {
    __shared__ __align__(16) ushortT Al[128][40];
    __shared__ __align__(16) ushortT Bl[32][40];
    int mt = blockIdx.x * 32;
    int ot = blockIdx.y * 128;
    int t = threadIdx.x, w = t >> 6, lane = t & 63, u = lane & 15, quad = lane >> 4;
    int r4 = t >> 2, ch = t & 3;

    const ushortT* pA0 = woutb + (size_t)(ot + r4) * 512 + ch * 8;
    const ushortT* pA1 = woutb + (size_t)(ot + 64 + r4) * 512 + ch * 8;
    uint4 ra0 = *(const uint4*)pA0;
    uint4 ra1 = *(const uint4*)pA1;

    // B staging: threads t<128 handle the 32-row Opart tile (row = t>>2 in 0..31)
    const ushortT* pO0 = 0; const ushortT* pO1 = 0;
    uint4 ro0 = {}, ro1 = {};
    float linv[8];
    int bm = mt + r4;
    if (t < 128) {
        #pragma unroll
        for (int h = 0; h < 8; h++)
            linv[h] = 1.f / (liPart[(size_t)bm * 8 + h] + liPart[(size_t)(8192 + bm) * 8 + h]);
        pO0 = Opart + (size_t)bm * 512 + ch * 8;
        pO1 = Opart + (size_t)(8192 + bm) * 512 + ch * 8;
        ro0 = *(const uint4*)pO0;
        ro1 = *(const uint4*)pO1;
    }

    v4f acc[2][2] = {};
    for (int k0 = 0; k0 < 512; k0 += 32) {
        *(uint4*)&Al[r4][ch * 8] = ra0;
        *(uint4*)&Al[64 + r4][ch * 8] = ra1;
        if (t < 128) {
            int h = (k0 + ch * 8) >> 6;
            float iv = linv[h];
            uint4 bv;
            bv.x = pack2bf((bflo(ro0.x) + bflo(ro1.x)) * iv, (bfhi(ro0.x) + bfhi(ro1.x)) * iv);
            bv.y = pack2bf((bflo(ro0.y) + bflo(ro1.y)) * iv, (bfhi(ro0.y) + bfhi(ro1.y)) * iv);
            bv.z = pack2bf((bflo(ro0.z) + bflo(ro1.z)) * iv, (bfhi(ro0.z) + bfhi(ro1.z)) * iv);
            bv.w = pack2bf((bflo(ro0.w) + bflo(ro1.w)) * iv, (bfhi(ro0.w) + bfhi(ro1.w)) * iv);
            *(uint4*)&Bl[r4][ch * 8] = bv;
        }
        __syncthreads();
        if (k0 + 32 < 512) {
            pA0 += 32; pA1 += 32;
            ra0 = *(const uint4*)pA0;
            ra1 = *(const uint4*)pA1;
            if (t < 128) {
                pO0 += 32; pO1 += 32;
                ro0 = *(const uint4*)pO0;
                ro1 = *(const uint4*)pO1;
            }
        }
        v8s a[2], bb[2];
        a[0] = *(v8s*)&Al[w * 32 + u][quad * 8];
        a[1] = *(v8s*)&Al[w * 32 + 16 + u][quad * 8];
        bb[0] = *(v8s*)&Bl[u][quad * 8];
        bb[1] = *(v8s*)&Bl[16 + u][quad * 8];
        acc[0][0] = __builtin_amdgcn_mfma_f32_16x16x32_bf16(a[0], bb[0], acc[0][0], 0, 0, 0);
        acc[0][1] = __builtin_amdgcn_mfma_f32_16x16x32_bf16(a[0], bb[1], acc[0][1], 0, 0, 0);
        acc[1][0] = __builtin_amdgcn_mfma_f32_16x16x32_bf16(a[1], bb[0], acc[1][0], 0, 0, 0);
        acc[1][1] = __builtin_amdgcn_mfma_f32_16x16x32_bf16(a[1], bb[1], acc[1][1], 0, 0, 0);
        __syncthreads();
    }
    int b = mt >> 12, n0 = mt & 4095;
    #pragma unroll
    for (int rr = 0; rr < 2; rr++) {
        int obase = ot + w * 32 + rr * 16 + quad * 4;
        float bo[4];
        #pragma unroll
        for (int r = 0; r < 4; r++) bo[r] = bout[obase + r];
        #pragma unroll
        for (int n4 = 0; n4 < 2; n4++) {
            int n = n0 + n4 * 16 + u;
            float al = alpha[(size_t)b * NPOS + n];
            #pragma unroll
            for (int r = 0; r < 4; r++) {
                size_t xi = ((size_t)(b * 256 + obase + r)) * NPOS + n;
                out[xi] = x[xi] + (acc[rr][n4][r] + bo[r]) * al;
            }
        }
    }
}

extern "C" void kernel_launch(void* const* d_in, const int* in_sizes, int n_in,
                              void* d_out, int out_size, void* d_ws, size_t ws_size,
                              hipStream_t stream) {
    const float* x      = (const float*)d_in[0];
    const float* dsm    = (const float*)d_in[1];
    const float* wq     = (const float*)d_in[2];
    const float* wkv    = (const float*)d_in[3];
    const float* wout   = (const float*)d_in[4];
    const float* bout   = (const float*)d_in[5];
    const float* whape  = (const float*)d_in[6];
    const float* bhape  = (const float*)d_in[7];
    const float* walpha = (const float*)d_in[8];
    const float* balpha = (const float*)d_in[9];
    float* out = (float*)d_out;
    float* ws  = (float*)d_ws;

    size_t off = 0;
    float* alpha = ws + off; off += (size_t)2 * NPOS;
    float* biasc = ws + off; off += 2048;
    float* liPart = ws + off; off += (size_t)NSPLIT * MTOT * 8;
    ushortT* Opart = (ushortT*)(ws + off); off += (size_t)NSPLIT * MTOT * 512 / 2;
    ushortT* F     = (ushortT*)(ws + off); off += (size_t)MTOT * KP / 2;
    ushortT* Wc    = (ushortT*)(ws + off); off += (size_t)1536 * KP / 2;
    ushortT* woutb = (ushortT*)(ws + off); off += (size_t)256 * 512 / 2;
    ushortT* qT    = (ushortT*)(ws + off); off += (size_t)8 * MTOT * 64 / 2;
    ushortT* kT    = (ushortT*)(ws + off); off += (size_t)8 * MTOT * 64 / 2;
    ushortT* vv    = (ushortT*)(ws + off); off += (size_t)512 * MTOT / 2;
    (void)in_sizes; (void)n_in; (void)out_size; (void)ws_size;

    k_pre<<<2656, 256, 0, stream>>>(dsm, walpha, balpha, x, wq, wkv, whape, bhape, wout,
                                    F, alpha, Wc, biasc, woutb);
    k_gemm1<<<768, 256, 0, stream>>>(Wc, F, biasc, qT, kT, vv);
    k_flash<<<1024, 256, 0, stream>>>(qT, kT, vv, Opart, liPart);
    k_gemm2<<<dim3(256, 2), 256, 0, stream>>>(woutb, Opart, liPart, bout, x, alpha, out);
}